// Round 5
// baseline (16383.046 us; speedup 1.0000x reference)
//
#include <hip/hip_runtime.h>
#include <cstddef>
#include <cstdint>

#define DEVINL __device__ __forceinline__

constexpr int Bn = 128;   // batch
constexpr int Tn = 512;   // time
constexpr int Fn = 512;   // features
constexpr int Un = 256;   // units
constexpr int Gn = 1024;  // 4*U
constexpr int RS = 5;     // ring slots

typedef _Float16 h2t   __attribute__((ext_vector_type(2)));
typedef _Float16 half4 __attribute__((ext_vector_type(4)));
typedef _Float16 half8 __attribute__((ext_vector_type(8)));
typedef float    f32x4 __attribute__((ext_vector_type(4)));

DEVINL float ftanh(float x) { float e = __expf(2.f * x); return 1.f - 2.f / (e + 1.f); }
DEVINL float hsig(float x)  { return fminf(fmaxf(fmaf(x, 0.2f, 0.5f), 0.f), 1.f); }

DEVINL void softmax4(float* s) {
    float mx = fmaxf(fmaxf(s[0], s[1]), fmaxf(s[2], s[3]));
    float e0 = __expf(s[0] - mx), e1 = __expf(s[1] - mx);
    float e2 = __expf(s[2] - mx), e3 = __expf(s[3] - mx);
    float inv = 1.f / (e0 + e1 + e2 + e3);
    s[0] = e0 * inv; s[1] = e1 * inv; s[2] = e2 * inv; s[3] = e3 * inv;
}

DEVINL float d2(unsigned int w, unsigned int h, float acc) {
#if __has_builtin(__builtin_amdgcn_fdot2)
    return __builtin_amdgcn_fdot2(__builtin_bit_cast(h2t, w), __builtin_bit_cast(h2t, h), acc, false);
#else
    h2t a = __builtin_bit_cast(h2t, w), b = __builtin_bit_cast(h2t, h);
    acc = fmaf((float)a.x, (float)b.x, acc);
    acc = fmaf((float)a.y, (float)b.y, acc);
    return acc;
#endif
}
DEVINL float dot8h(uint4 w, uint4 h, float acc) {
    acc = d2(w.x, h.x, acc);
    acc = d2(w.y, h.y, acc);
    acc = d2(w.z, h.z, acc);
    acc = d2(w.w, h.w, acc);
    return acc;
}

// agent-scope (device-coherent, L1/L2-bypassing) exchange primitives
DEVINL void ast_u32(unsigned int* p, unsigned int v) {
    __hip_atomic_store(p, v, __ATOMIC_RELAXED, __HIP_MEMORY_SCOPE_AGENT);
}
DEVINL unsigned int ald_u32(const unsigned int* p) {
    return __hip_atomic_load(p, __ATOMIC_RELAXED, __HIP_MEMORY_SCOPE_AGENT);
}
DEVINL void ast_f32(float* p, float v) {
    __hip_atomic_store(p, v, __ATOMIC_RELAXED, __HIP_MEMORY_SCOPE_AGENT);
}
DEVINL float ald_f32(const float* p) {
    return __hip_atomic_load(p, __ATOMIC_RELAXED, __HIP_MEMORY_SCOPE_AGENT);
}

// ---------------------------------------------------------------------------
__global__ __launch_bounds__(256)
void pack_x(const float* __restrict__ x, _Float16* __restrict__ xh)
{
    size_t i = ((size_t)blockIdx.x * 256 + threadIdx.x) * 4;
    float4 v = *(const float4*)(x + i);
    half4 o;
    o.x = (_Float16)v.x; o.y = (_Float16)v.y; o.z = (_Float16)v.z; o.w = (_Float16)v.w;
    *(half4*)(xh + i) = o;
}

__global__ __launch_bounds__(256)
void wt_pack(const float* __restrict__ W, _Float16* __restrict__ Wt, int N)
{
    int total = N * 512;
    for (int e = blockIdx.x * 256 + threadIdx.x; e < total; e += gridDim.x * 256) {
        int n = e >> 9, k = e & 511;
        Wt[e] = (_Float16)W[(size_t)k * N + n];
    }
}

__global__ __launch_bounds__(256)
void pack_w(const float* __restrict__ rk, const float* __restrict__ ath,
            const float* __restrict__ atc,
            _Float16* __restrict__ rkP, _Float16* __restrict__ WhP,
            _Float16* __restrict__ WcP)
{
    int idx = blockIdx.x * 256 + threadIdx.x;
    const int stride = gridDim.x * 256;
    for (int e = idx; e < 32 * 1024 * 8; e += stride) {
        int i = e & 7, n = (e >> 3) & 1023, kc = e >> 13;
        rkP[e] = (_Float16)rk[(size_t)(kc * 8 + i) * Gn + n];
    }
    for (int e = idx; e < 32 * 256 * 8; e += stride) {
        int i = e & 7, n = (e >> 3) & 255, kc = e >> 11;
        WhP[e] = (_Float16)ath[(size_t)(kc * 8 + i) * Un + n];
        WcP[e] = (_Float16)atc[(size_t)(kc * 8 + i) * Un + n];
    }
}

// ---------------------------------------------------------------------------
template<bool TMAJ>
__global__ __launch_bounds__(256)
void gemm_mfma(const _Float16* __restrict__ A, const _Float16* __restrict__ Wt,
               int N, _Float16* __restrict__ out)
{
    __shared__ __align__(16) _Float16 As[64][40];
    __shared__ __align__(16) _Float16 Bs[64][40];
    const int tid = threadIdx.x;
    const int n0 = blockIdx.x * 64, m0 = blockIdx.y * 64;
    const int w = tid >> 6, lane = tid & 63;
    const int fr = lane & 15, quad = lane >> 4;
    const int srow = tid >> 2, sk = (tid & 3) * 8;

    f32x4 acc[4];
    #pragma unroll
    for (int i = 0; i < 4; i++) acc[i] = (f32x4){0.f, 0.f, 0.f, 0.f};

    const _Float16* ap = A  + (size_t)(m0 + srow) * 512 + sk;
    const _Float16* bp = Wt + (size_t)(n0 + srow) * 512 + sk;

    for (int k0 = 0; k0 < 512; k0 += 32) {
        uint4 av = *(const uint4*)(ap + k0);
        uint4 bv = *(const uint4*)(bp + k0);
        __syncthreads();
        *(uint4*)&As[srow][sk] = av;
        *(uint4*)&Bs[srow][sk] = bv;
        __syncthreads();
        half8 a = *(const half8*)&As[w * 16 + fr][quad * 8];
        #pragma unroll
        for (int nt = 0; nt < 4; nt++) {
            half8 b = *(const half8*)&Bs[nt * 16 + fr][quad * 8];
            acc[nt] = __builtin_amdgcn_mfma_f32_16x16x32_f16(a, b, acc[nt], 0, 0, 0);
        }
    }
    #pragma unroll
    for (int nt = 0; nt < 4; nt++) {
        int n = n0 + nt * 16 + fr;
        #pragma unroll
        for (int reg = 0; reg < 4; reg++) {
            int m = m0 + w * 16 + quad * 4 + reg;
            if (TMAJ) {
                int b = m >> 9, t = m & 511;
                out[((size_t)t * Bn + b) * N + n] = (_Float16)acc[nt][reg];
            } else {
                out[(size_t)m * N + n] = (_Float16)acc[nt][reg];
            }
        }
    }
}

// ---------------------------------------------------------------------------
// Phase 2: distributed recurrence. 32 groups x 8 WGs (grid 256, 512 thr,
// 1 WG/CU). Each WG keeps a 1/8 column-slice of ALL recurrence weights in
// LDS permanently (96 KB dynamic) -> the 768 KB/step/CU L2 weight stream
// (the measured round-2/3/4 bound) is eliminated. WG s of group g owns
// stream row g*8+s (rings local). Per step: 4 group barriers via agent-scope
// counter; inter-WG data via agent-scope atomics (L3-coherent, placement-
// independent).
// ---------------------------------------------------------------------------
__global__ __launch_bounds__(512)
void recurrence(const _Float16* __restrict__ xg,
                const _Float16* __restrict__ xWh,
                const _Float16* __restrict__ xWc,
                const _Float16* __restrict__ rkP,
                const _Float16* __restrict__ WhP,
                const _Float16* __restrict__ WcP,
                _Float16* __restrict__ outs,
                unsigned int* __restrict__ Xhm,
                unsigned int* __restrict__ XH,
                unsigned int* __restrict__ XC,
                float* __restrict__ Xg,
                float* __restrict__ Xph,
                float* __restrict__ Xpch,
                float* __restrict__ Xpcc,
                unsigned int* __restrict__ cnt)
{
    const int tid = threadIdx.x;
    const int grp = blockIdx.x & 31;   // group; members share blockIdx%32 -> same XCD under %8 round-robin
    const int s   = blockIdx.x >> 5;   // member 0..7: weight slice + owned row
    const int rowId = grp * 8 + s;
    const int d = rowId >> 7, b = rowId & 127;

    __shared__ float Hr[RS][Un], Cr[RS][Un];
    __shared__ float PHr[RS][Un], PCcr[RS][Un], PChr[RS][Un];
    __shared__ float gtmp[4][Un];
    __shared__ __align__(16) unsigned int hmS[8][128];
    __shared__ __align__(16) unsigned int HSs[8][128], CSs[8][128];
    __shared__ __align__(16) float red[8][4];
    __shared__ int sync_dead;

    extern __shared__ uint4 dynv[];            // 96 KB dynamic LDS
    uint4* rkA = dynv;                         // [32 kc][128 cols]
    uint4* WhA = dynv + 32 * 128;              // [32 kc][32 cols]
    uint4* WcA = WhA + 32 * 32;                // [32 kc][32 cols]

    // one-time: load weight slices into LDS
    {
        const uint4* rkG = (const uint4*)rkP;  // [(kc*1024 + n)]
        for (int e = tid; e < 32 * 128; e += 512) {
            int kc = e >> 7, c = e & 127;
            rkA[e] = rkG[kc * 1024 + s * 128 + c];
        }
        const uint4* whG = (const uint4*)WhP;  // [(kc*256 + n)]
        const uint4* wcG = (const uint4*)WcP;
        for (int e = tid; e < 32 * 32; e += 512) {
            int kc = e >> 5, c = e & 31;
            WhA[e] = whG[kc * 256 + s * 32 + c];
            WcA[e] = wcG[kc * 256 + s * 32 + c];
        }
    }
    for (int e = tid; e < RS * Un; e += 512) {
        ((float*)Hr)[e] = 0.f; ((float*)Cr)[e] = 0.f;
        ((float*)PHr)[e] = 0.f; ((float*)PCcr)[e] = 0.f; ((float*)PChr)[e] = 0.f;
    }
    if (tid == 0) sync_dead = 0;
    __syncthreads();

    unsigned int* myCnt = cnt + grp * 64;      // padded counters
    unsigned int tgt = 8;

    const int u = tid & 255;
    const int g = tid >> 8;                    // score family: 0 = h, 1 = c
    const int lane = tid & 63;
    const int gwv = (tid >> 6) & 3;
    const size_t gb128 = (size_t)grp * 8 * 128;

    // group barrier: arrive (release) + spin (acquire); guarded against hang
    auto gsync = [&](unsigned int target) {
        __syncthreads();
        if (tid == 0) {
            __hip_atomic_fetch_add(myCnt, 1u, __ATOMIC_ACQ_REL, __HIP_MEMORY_SCOPE_AGENT);
            if (!sync_dead) {
                int guard = 0;
                while (__hip_atomic_load(myCnt, __ATOMIC_ACQUIRE, __HIP_MEMORY_SCOPE_AGENT) < target) {
                    __builtin_amdgcn_s_sleep(2);
                    if (++guard > 2000000) { sync_dead = 1; break; }
                }
            }
        }
        __syncthreads();
    };

    for (int t = 0; t < Tn; t++) {
        const int tt = d ? (Tn - 1 - t) : t;
        const int st = t % RS;
        int sj[4];
        #pragma unroll
        for (int j = 0; j < 4; j++) sj[j] = (t - 1 - j + 2 * RS) % RS;
        const size_t rowx = (size_t)tt * Bn + b;

        // step inputs (HBM; issued early, consumed late)
        float xh = (float)xWh[rowx * Un + u];
        float xc = (float)xWc[rowx * Un + u];
        float xg0 = 0.f, xg1 = 0.f, xg2 = 0.f, xg3 = 0.f;
        if (tid < 256) {
            xg0 = (float)xg[rowx * Gn + u];
            xg1 = (float)xg[rowx * Gn + Un + u];
            xg2 = (float)xg[rowx * Gn + 2 * Un + u];
            xg3 = (float)xg[rowx * Gn + 3 * Un + u];
        }

        // ---- P0a: gather previous step's projection partials into rings ----
        if (t > 0) {
            if (tid < 256) {
                int slot = (t - 1) % RS;
                int src = tid >> 5, c5 = tid & 31;
                size_t pb = ((size_t)(grp * 8 + src) * 8 + s) * 32 + c5;   // col = tid
                PHr[slot][tid]  = ald_f32(Xph + pb);
                PChr[slot][tid] = ald_f32(Xpch + pb);
                PCcr[slot][tid] = ald_f32(Xpcc + pb);
            }
            __syncthreads();
        }

        // ---- P0b: scores (own row; family split) ----
        float vals[4];
        if (g == 0) {
            #pragma unroll
            for (int j = 0; j < 4; j++) {
                float ah = ftanh(PHr[sj[j]][u] + xh);
                vals[j] = ah * ah;
            }
        } else {
            #pragma unroll
            for (int j = 0; j < 4; j++) {
                float pc = (j < 3) ? PCcr[sj[j]][u] : PChr[sj[j]][u];
                float ac = ftanh(pc + ((j < 3) ? xc : xh));
                vals[j] = ac * ac;
            }
        }
        #pragma unroll
        for (int jj = 0; jj < 4; jj++) {
            float v = vals[jj];
            #pragma unroll
            for (int m = 32; m; m >>= 1) v += __shfl_xor(v, m, 64);
            if (lane == 0) red[g * 4 + jj][gwv] = v;
        }
        __syncthreads();

        // ---- P0c: softmax + hmix/cmix + publish hm ----
        float cmv = 0.f;
        if (tid < 256) {
            float sh[4], sc[4];
            #pragma unroll
            for (int j = 0; j < 4; j++) {
                float4 ph  = *(const float4*)red[j];
                float4 pcv = *(const float4*)red[4 + j];
                sh[j] = sqrtf(ph.x + ph.y + ph.z + ph.w);
                sc[j] = sqrtf(pcv.x + pcv.y + pcv.z + pcv.w);
            }
            softmax4(sh); softmax4(sc);
            float ha = 0.f, ca = 0.f;
            #pragma unroll
            for (int j = 0; j < 4; j++) {
                ha = fmaf(sh[j], Hr[sj[j]][u], ha);
                ca = fmaf(sc[j], Cr[sj[j]][u], ca);
            }
            float hmv = fmaxf(ha, 0.f);
            cmv = fmaxf(ca, 0.f);
            float ho = __shfl_xor(hmv, 1, 64);
            if (!(tid & 1)) {
                h2t pk; pk.x = (_Float16)hmv; pk.y = (_Float16)ho;
                ast_u32(Xhm + (size_t)rowId * 128 + (u >> 1),
                        __builtin_bit_cast(unsigned int, pk));
            }
        }
        gsync(tgt); tgt += 8;                       // S1: hm of all rows published

        // ---- P1: gate partial GEMV (my 128 cols x all 8 rows, LDS weights) ----
        for (int e = tid; e < 1024; e += 512)
            hmS[e >> 7][e & 127] = ald_u32(Xhm + gb128 + e);
        __syncthreads();
        {
            const int col = tid & 127, rp = tid >> 7;   // row pair
            const uint4* hv0 = (const uint4*)hmS[rp * 2];
            const uint4* hv1 = (const uint4*)hmS[rp * 2 + 1];
            float a0 = 0.f, a1 = 0.f;
            #pragma unroll 4
            for (int kc = 0; kc < 32; kc++) {
                uint4 w = rkA[kc * 128 + col];
                a0 = dot8h(w, hv0[kc], a0);
                a1 = dot8h(w, hv1[kc], a1);
            }
            ast_f32(Xg + ((size_t)rowId * 8 + rp * 2) * 128 + col, a0);
            ast_f32(Xg + ((size_t)rowId * 8 + rp * 2 + 1) * 128 + col, a1);
        }
        gsync(tgt); tgt += 8;                       // S2: gate partials published

        // ---- P2: owner gathers own row's g; gates epilogue ----
        for (int e = tid; e < 1024; e += 512) {
            int src = e >> 7, cl = e & 127;
            float gv = ald_f32(Xg + ((size_t)(grp * 8 + src) * 8 + s) * 128 + cl);
            int C = src * 128 + cl;
            gtmp[C >> 8][C & 255] = gv;
        }
        __syncthreads();
        if (tid < 256) {
            float g0 = gtmp[0][u] + xg0;
            float g1 = gtmp[1][u] + xg1;
            float g2 = gtmp[2][u] + xg2;
            float g3 = gtmp[3][u] + xg3;
            float gi = hsig(g0), gf = hsig(g1), gm = hsig(g2), go = hsig(g3);
            float c = gf * cmv + gi * gm;
            float h = go * ftanh(c);
            Hr[st][u] = h;
            Cr[st][u] = c;
            outs[((size_t)b * Tn + tt) * 512 + d * 256 + u] = (_Float16)h;
            float hho = __shfl_xor(h, 1, 64);
            float cco = __shfl_xor(c, 1, 64);
            if (!(tid & 1)) {
                h2t pk1; pk1.x = (_Float16)h; pk1.y = (_Float16)hho;
                h2t pk2; pk2.x = (_Float16)c; pk2.y = (_Float16)cco;
                ast_u32(XH + (size_t)rowId * 128 + (u >> 1),
                        __builtin_bit_cast(unsigned int, pk1));
                ast_u32(XC + (size_t)rowId * 128 + (u >> 1),
                        __builtin_bit_cast(unsigned int, pk2));
            }
        }
        gsync(tgt); tgt += 8;                       // S3: H/C of all rows published

        // ---- P3: projection partials (my 32 cols x all 8 rows) ----
        for (int e = tid; e < 1024; e += 512) {
            HSs[e >> 7][e & 127] = ald_u32(XH + gb128 + e);
            CSs[e >> 7][e & 127] = ald_u32(XC + gb128 + e);
        }
        __syncthreads();
        if (tid < 256) {
            int rr = tid >> 5, c = tid & 31;
            const uint4* Hv = (const uint4*)HSs[rr];
            const uint4* Cv = (const uint4*)CSs[rr];
            float ph = 0.f, pch = 0.f;
            #pragma unroll 4
            for (int kc = 0; kc < 32; kc++) {
                uint4 w = WhA[kc * 32 + c];
                ph  = dot8h(w, Hv[kc], ph);
                pch = dot8h(w, Cv[kc], pch);
            }
            size_t pb = ((size_t)rowId * 8 + rr) * 32 + c;
            ast_f32(Xph + pb, ph);
            ast_f32(Xpch + pb, pch);
        } else {
            int i = tid - 256, rr = i >> 5, c = i & 31;
            const uint4* Cv = (const uint4*)CSs[rr];
            float pcc = 0.f;
            #pragma unroll 4
            for (int kc = 0; kc < 32; kc++) {
                uint4 w = WcA[kc * 32 + c];
                pcc = dot8h(w, Cv[kc], pcc);
            }
            ast_f32(Xpcc + ((size_t)rowId * 8 + rr) * 32 + c, pcc);
        }
        gsync(tgt); tgt += 8;                       // S4: proj partials published
    }
}

// ---------------------------------------------------------------------------
DEVINL void cvt8(uint4 v, float* f) {
    h2t p0 = __builtin_bit_cast(h2t, v.x), p1 = __builtin_bit_cast(h2t, v.y);
    h2t p2 = __builtin_bit_cast(h2t, v.z), p3 = __builtin_bit_cast(h2t, v.w);
    f[0] = (float)p0.x; f[1] = (float)p0.y; f[2] = (float)p1.x; f[3] = (float)p1.y;
    f[4] = (float)p2.x; f[5] = (float)p2.y; f[6] = (float)p3.x; f[7] = (float)p3.y;
}

__global__ __launch_bounds__(256)
void final2(const _Float16* __restrict__ t1, const _Float16* __restrict__ t2,
            const _Float16* __restrict__ outs16,
            const float* __restrict__ at2, const float* __restrict__ at22,
            float* __restrict__ out)
{
    __shared__ float has[8], hbs[8];
    const int tid = threadIdx.x;
    const size_t m0 = (size_t)blockIdx.x * 8;
    const int rr = tid >> 5, us = tid & 31;
    const size_t m = m0 + rr;

    uint4 v1 = *(const uint4*)(t1 + m * 256 + us * 8);
    uint4 v2 = *(const uint4*)(t2 + m * 256 + us * 8);
    float f1[8], f2[8];
    cvt8(v1, f1); cvt8(v2, f2);
    float4 wa0 = *(const float4*)(at2  + us * 8);
    float4 wa1 = *(const float4*)(at2  + us * 8 + 4);
    float4 wb0 = *(const float4*)(at22 + us * 8);
    float4 wb1 = *(const float4*)(at22 + us * 8 + 4);

    float pa = fmaxf(f1[0], 0.f) * wa0.x + fmaxf(f1[1], 0.f) * wa0.y
             + fmaxf(f1[2], 0.f) * wa0.z + fmaxf(f1[3], 0.f) * wa0.w
             + fmaxf(f1[4], 0.f) * wa1.x + fmaxf(f1[5], 0.f) * wa1.y
             + fmaxf(f1[6], 0.f) * wa1.z + fmaxf(f1[7], 0.f) * wa1.w;
    float pb = fmaxf(f2[0], 0.f) * wb0.x + fmaxf(f2[1], 0.f) * wb0.y
             + fmaxf(f2[2], 0.f) * wb0.z + fmaxf(f2[3], 0.f) * wb0.w
             + fmaxf(f2[4], 0.f) * wb1.x + fmaxf(f2[5], 0.f) * wb1.y
             + fmaxf(f2[6], 0.f) * wb1.z + fmaxf(f2[7], 0.f) * wb1.w;
    #pragma unroll
    for (int mm = 16; mm; mm >>= 1) {
        pa += __shfl_xor(pa, mm, 32);
        pb += __shfl_xor(pb, mm, 32);
    }
    if (us == 0) { has[rr] = pa; hbs[rr] = pb; }
    __syncthreads();

    for (int e = tid; e < 8 * 128; e += 256) {
        int r2 = e >> 7, k4 = (e & 127) * 4;
        size_t base = (m0 + r2) * 512 + k4;
        uint2 hv = *(const uint2*)(outs16 + base);
        h2t pA = __builtin_bit_cast(h2t, hv.x), pB = __builtin_bit_cast(h2t, hv.y);
        float hav = has[r2], hbv = hbs[r2];
        float4 o;
        o.x = ftanh(hav * (float)pA.x + hbv);
        o.y = ftanh(hav * (float)pA.y + hbv);
        o.z = ftanh(hav * (float)pB.x + hbv);
        o.w = ftanh(hav * (float)pB.y + hbv);
        *(float4*)(out + base) = o;
    }
}

// ---------------------------------------------------------------------------
extern "C" void kernel_launch(void* const* d_in, const int* in_sizes, int n_in,
                              void* d_out, int out_size, void* d_ws, size_t ws_size,
                              hipStream_t stream)
{
    (void)in_sizes; (void)n_in; (void)out_size; (void)ws_size;
    const float* x    = (const float*)d_in[0];
    const float* wk   = (const float*)d_in[1];
    const float* rk   = (const float*)d_in[2];
    const float* ath  = (const float*)d_in[3];
    const float* atc  = (const float*)d_in[4];
    const float* at1  = (const float*)d_in[5];
    const float* at2  = (const float*)d_in[7];
    const float* at22 = (const float*)d_in[8];
    float* out = (float*)d_out;

    char* p = (char*)d_ws;
    auto take = [&](size_t bytes) { char* q = p; p += (bytes + 255) & ~(size_t)255; return q; };
    _Float16* xg   = (_Float16*)take((size_t)Tn * Bn * Gn * 2);
    _Float16* xWh  = (_Float16*)take((size_t)Tn * Bn * Un * 2);
    _Float16* xWc  = (_Float16*)take((size_t)Tn * Bn * Un * 2);
    _Float16* A16  = (_Float16*)take((size_t)Bn * Tn * 512 * 2);
    _Float16* xf16 = (_Float16*)take((size_t)Bn * Tn * Fn * 2);
    _Float16* rkP  = (_Float16*)take((size_t)Un * Gn * 2);
    _Float16* WhP  = (_Float16*)take((size_t)Un * Un * 2);
    _Float16* WcP  = (_Float16*)take((size_t)Un * Un * 2);
    _Float16* Wt1  = (_Float16*)take((size_t)Gn * Fn * 2);
    _Float16* Wt2  = (_Float16*)take((size_t)Un * Fn * 2);
    _Float16* Wt3  = (_Float16*)take((size_t)Un * Fn * 2);
    _Float16* WtA  = (_Float16*)take((size_t)Un * Fn * 2);
    _Float16* WtB  = (_Float16*)take((size_t)Un * Fn * 2);
    // exchange buffers for distributed recurrence (~2.1 MB)
    unsigned int* Xhm = (unsigned int*)take(32 * 8 * 128 * 4);
    unsigned int* XH  = (unsigned int*)take(32 * 8 * 128 * 4);
    unsigned int* XC  = (unsigned int*)take(32 * 8 * 128 * 4);
    float* Xg   = (float*)take((size_t)32 * 8 * 8 * 128 * 4);
    float* Xph  = (float*)take(32 * 8 * 8 * 32 * 4);
    float* Xpch = (float*)take(32 * 8 * 8 * 32 * 4);
    float* Xpcc = (float*)take(32 * 8 * 8 * 32 * 4);
    unsigned int* cnt = (unsigned int*)take(32 * 64 * 4);
    _Float16* t1 = (_Float16*)xg;
    _Float16* t2 = t1 + (size_t)Bn * Tn * Un;

    // Phase 0: packing
    pack_x<<<32768, 256, 0, stream>>>(x, xf16);
    wt_pack<<<2048, 256, 0, stream>>>(wk, Wt1, Gn);
    wt_pack<<<1024, 256, 0, stream>>>(ath + (size_t)Un * Un, Wt2, Un);
    wt_pack<<<1024, 256, 0, stream>>>(atc + (size_t)Un * Un, Wt3, Un);
    wt_pack<<<1024, 256, 0, stream>>>(at1, WtA, Un);
    wt_pack<<<1024, 256, 0, stream>>>(at1 + (size_t)512 * Un, WtB, Un);
    pack_w<<<64, 256, 0, stream>>>(rk, ath, atc, rkP, WhP, WcP);

    // Phase 1: MFMA x-projections
    gemm_mfma<true><<<dim3(Gn / 64, (Bn * Tn) / 64), 256, 0, stream>>>(xf16, Wt1, Gn, xg);
    gemm_mfma<true><<<dim3(Un / 64, (Bn * Tn) / 64), 256, 0, stream>>>(xf16, Wt2, Un, xWh);
    gemm_mfma<true><<<dim3(Un / 64, (Bn * Tn) / 64), 256, 0, stream>>>(xf16, Wt3, Un, xWc);

    // Phase 2: distributed recurrence (32 groups x 8 WGs, LDS-resident weights)
    hipMemsetAsync(cnt, 0, 32 * 64 * 4, stream);
    hipFuncSetAttribute(reinterpret_cast<const void*>(recurrence),
                        hipFuncAttributeMaxDynamicSharedMemorySize, 98304);
    recurrence<<<dim3(256), dim3(512), 98304, stream>>>(
        xg, xWh, xWc, rkP, WhP, WcP, A16,
        Xhm, XH, XC, Xg, Xph, Xpch, Xpcc, cnt);

    // Phase 3: output attention as two MFMA GEMMs + light epilogue
    gemm_mfma<false><<<dim3(Un / 64, (Bn * Tn) / 64), 256, 0, stream>>>(A16,  WtA, Un, t1);
    gemm_mfma<false><<<dim3(Un / 64, (Bn * Tn) / 64), 256, 0, stream>>>(xf16, WtB, Un, t2);
    final2<<<(Bn * Tn) / 8, 256, 0, stream>>>(t1, t2, A16, at2, at22, out);
}

// Round 6
// 13865.758 us; speedup vs baseline: 1.1815x; 1.1815x over previous
//
#include <hip/hip_runtime.h>
#include <cstddef>
#include <cstdint>

#define DEVINL __device__ __forceinline__

constexpr int Bn = 128;   // batch
constexpr int Tn = 512;   // time
constexpr int Fn = 512;   // features
constexpr int Un = 256;   // units
constexpr int Gn = 1024;  // 4*U
constexpr int RS = 5;     // ring slots

typedef _Float16 h2t   __attribute__((ext_vector_type(2)));
typedef _Float16 half4 __attribute__((ext_vector_type(4)));
typedef _Float16 half8 __attribute__((ext_vector_type(8)));
typedef float    f32x4 __attribute__((ext_vector_type(4)));

DEVINL float ftanh(float x) { float e = __expf(2.f * x); return 1.f - 2.f / (e + 1.f); }
DEVINL float hsig(float x)  { return fminf(fmaxf(fmaf(x, 0.2f, 0.5f), 0.f), 1.f); }

DEVINL void softmax4(float* s) {
    float mx = fmaxf(fmaxf(s[0], s[1]), fmaxf(s[2], s[3]));
    float e0 = __expf(s[0] - mx), e1 = __expf(s[1] - mx);
    float e2 = __expf(s[2] - mx), e3 = __expf(s[3] - mx);
    float inv = 1.f / (e0 + e1 + e2 + e3);
    s[0] = e0 * inv; s[1] = e1 * inv; s[2] = e2 * inv; s[3] = e3 * inv;
}

// dot of 2 fp16 pairs: w (packed f16x2 as uint) . h -> acc
DEVINL float d2(unsigned int w, unsigned int h, float acc) {
#if __has_builtin(__builtin_amdgcn_fdot2)
    return __builtin_amdgcn_fdot2(__builtin_bit_cast(h2t, w), __builtin_bit_cast(h2t, h), acc, false);
#else
    h2t a = __builtin_bit_cast(h2t, w), b = __builtin_bit_cast(h2t, h);
    acc = fmaf((float)a.x, (float)b.x, acc);
    acc = fmaf((float)a.y, (float)b.y, acc);
    return acc;
#endif
}
// 8 fp16 weights (uint4) . 8 fp16 h-values (uint4) -> acc
DEVINL float dot8h(uint4 w, uint4 h, float acc) {
    acc = d2(w.x, h.x, acc);
    acc = d2(w.y, h.y, acc);
    acc = d2(w.z, h.z, acc);
    acc = d2(w.w, h.w, acc);
    return acc;
}

// ---------------------------------------------------------------------------
// pack x (fp32) -> fp16, same layout (M=B*T rows, 512 cols)
// ---------------------------------------------------------------------------
__global__ __launch_bounds__(256)
void pack_x(const float* __restrict__ x, _Float16* __restrict__ xh)
{
    size_t i = ((size_t)blockIdx.x * 256 + threadIdx.x) * 4;
    float4 v = *(const float4*)(x + i);
    half4 o;
    o.x = (_Float16)v.x; o.y = (_Float16)v.y; o.z = (_Float16)v.z; o.w = (_Float16)v.w;
    *(half4*)(xh + i) = o;
}

// ---------------------------------------------------------------------------
// pack W (K=512 rows x N cols, fp32) -> Wt (N rows x 512 cols, fp16)
// ---------------------------------------------------------------------------
__global__ __launch_bounds__(256)
void wt_pack(const float* __restrict__ W, _Float16* __restrict__ Wt, int N)
{
    int total = N * 512;
    for (int e = blockIdx.x * 256 + threadIdx.x; e < total; e += gridDim.x * 256) {
        int n = e >> 9, k = e & 511;
        Wt[e] = (_Float16)W[(size_t)k * N + n];
    }
}

// ---------------------------------------------------------------------------
// pack recurrence weights -> fp16, k-interleaved: P[(kc*N + n)*8 + i] = W[kc*8+i][n]
// ---------------------------------------------------------------------------
__global__ __launch_bounds__(256)
void pack_w(const float* __restrict__ rk, const float* __restrict__ ath,
            const float* __restrict__ atc,
            _Float16* __restrict__ rkP, _Float16* __restrict__ WhP,
            _Float16* __restrict__ WcP)
{
    int idx = blockIdx.x * 256 + threadIdx.x;
    const int stride = gridDim.x * 256;
    for (int e = idx; e < 32 * 1024 * 8; e += stride) {
        int i = e & 7, n = (e >> 3) & 1023, kc = e >> 13;
        rkP[e] = (_Float16)rk[(size_t)(kc * 8 + i) * Gn + n];
    }
    for (int e = idx; e < 32 * 256 * 8; e += stride) {
        int i = e & 7, n = (e >> 3) & 255, kc = e >> 11;
        WhP[e] = (_Float16)ath[(size_t)(kc * 8 + i) * Un + n];
        WcP[e] = (_Float16)atc[(size_t)(kc * 8 + i) * Un + n];
    }
}

// ---------------------------------------------------------------------------
// MFMA fp16 GEMM. A: (65536 x 512) fp16 row-major. Wt: (N x 512) fp16
// (pre-transposed). TMAJ: out at [(t*B+b)*N+n] (m = b*512+t); else out[m*N+n].
// ---------------------------------------------------------------------------
template<bool TMAJ>
__global__ __launch_bounds__(256)
void gemm_mfma(const _Float16* __restrict__ A, const _Float16* __restrict__ Wt,
               int N, _Float16* __restrict__ out)
{
    __shared__ __align__(16) _Float16 As[64][40];
    __shared__ __align__(16) _Float16 Bs[64][40];
    const int tid = threadIdx.x;
    const int n0 = blockIdx.x * 64, m0 = blockIdx.y * 64;
    const int w = tid >> 6, lane = tid & 63;
    const int fr = lane & 15, quad = lane >> 4;
    const int srow = tid >> 2, sk = (tid & 3) * 8;

    f32x4 acc[4];
    #pragma unroll
    for (int i = 0; i < 4; i++) acc[i] = (f32x4){0.f, 0.f, 0.f, 0.f};

    const _Float16* ap = A  + (size_t)(m0 + srow) * 512 + sk;
    const _Float16* bp = Wt + (size_t)(n0 + srow) * 512 + sk;

    for (int k0 = 0; k0 < 512; k0 += 32) {
        uint4 av = *(const uint4*)(ap + k0);
        uint4 bv = *(const uint4*)(bp + k0);
        __syncthreads();
        *(uint4*)&As[srow][sk] = av;
        *(uint4*)&Bs[srow][sk] = bv;
        __syncthreads();
        half8 a = *(const half8*)&As[w * 16 + fr][quad * 8];
        #pragma unroll
        for (int nt = 0; nt < 4; nt++) {
            half8 b = *(const half8*)&Bs[nt * 16 + fr][quad * 8];
            acc[nt] = __builtin_amdgcn_mfma_f32_16x16x32_f16(a, b, acc[nt], 0, 0, 0);
        }
    }
    #pragma unroll
    for (int nt = 0; nt < 4; nt++) {
        int n = n0 + nt * 16 + fr;
        #pragma unroll
        for (int reg = 0; reg < 4; reg++) {
            int m = m0 + w * 16 + quad * 4 + reg;
            if (TMAJ) {
                int b = m >> 9, t = m & 511;
                out[((size_t)t * Bn + b) * N + n] = (_Float16)acc[nt][reg];
            } else {
                out[(size_t)m * N + n] = (_Float16)acc[nt][reg];
            }
        }
    }
}

// ---------------------------------------------------------------------------
// Phase 2: recurrence. 256 WGs x 512 threads; WG handles ONE (dir, batch) row.
// Round-4 validated structure; phases C/E rewritten as explicit 2-deep
// ping-pong pipelines (named register groups, static indices only) so the
// L2 weight stream runs at throughput, not exposed latency.
// ---------------------------------------------------------------------------
__global__ __launch_bounds__(512)
void recurrence(const _Float16* __restrict__ xg,
                const _Float16* __restrict__ xWh,
                const _Float16* __restrict__ xWc,
                const _Float16* __restrict__ rkP,
                const _Float16* __restrict__ WhP,
                const _Float16* __restrict__ WcP,
                _Float16* __restrict__ outs)
{
    const int tid = threadIdx.x;
    const int d = blockIdx.x >> 7;          // direction
    const int b = blockIdx.x & 127;         // batch row

    __shared__ float Hr[RS][Un], Cr[RS][Un];
    __shared__ float PHr[RS][Un], PCcr[RS][Un], PChr[RS][Un];
    __shared__ __align__(16) unsigned int hm_pk[128];
    __shared__ __align__(16) unsigned int Hpk[128], Cpk[128];
    __shared__ float gtmp[4][Un];
    __shared__ __align__(16) float red[8][4];

    for (int e = tid; e < RS * Un; e += 512) {
        ((float*)Hr)[e] = 0.f; ((float*)Cr)[e] = 0.f;
        ((float*)PHr)[e] = 0.f; ((float*)PCcr)[e] = 0.f; ((float*)PChr)[e] = 0.f;
    }
    __syncthreads();

    const int u = tid & 255;
    const int g = tid >> 8;            // score family: 0 = h, 1 = c
    const int lane = tid & 63;
    const int gwv = (tid >> 6) & 3;    // wave index within family

    for (int t = 0; t < Tn; t++) {
        const int tt = d ? (Tn - 1 - t) : t;
        const int st = t % RS;
        int sj[4];
        #pragma unroll
        for (int j = 0; j < 4; j++) sj[j] = (t - 1 - j + 2 * RS) % RS;

        const size_t rowx = (size_t)tt * Bn + b;

        // per-thread step inputs
        float xh = (float)xWh[rowx * Un + u];
        float xc = (float)xWc[rowx * Un + u];
        float xg0 = 0.f, xg1 = 0.f, xg2 = 0.f, xg3 = 0.f;
        if (tid < 256) {
            xg0 = (float)xg[rowx * Gn + u];
            xg1 = (float)xg[rowx * Gn + Un + u];
            xg2 = (float)xg[rowx * Gn + 2 * Un + u];
            xg3 = (float)xg[rowx * Gn + 3 * Un + u];
        }

        // ---- A: scores (4 tanh per thread; family g) ----
        float vals[4];
        if (g == 0) {
            #pragma unroll
            for (int j = 0; j < 4; j++) {
                float ah = ftanh(PHr[sj[j]][u] + xh);
                vals[j] = ah * ah;
            }
        } else {
            #pragma unroll
            for (int j = 0; j < 4; j++) {
                float pc = (j < 3) ? PCcr[sj[j]][u] : PChr[sj[j]][u];
                float ac = ftanh(pc + ((j < 3) ? xc : xh));
                vals[j] = ac * ac;
            }
        }
        #pragma unroll
        for (int jj = 0; jj < 4; jj++) {
            float v = vals[jj];
            #pragma unroll
            for (int m = 32; m; m >>= 1) v += __shfl_xor(v, m, 64);
            if (lane == 0) red[g * 4 + jj][gwv] = v;
        }
        __syncthreads();                                   // (1) red ready

        // ---- B: softmax + hmix/cmix + pack (tid < 256) ----
        float cmv = 0.f;
        if (tid < 256) {
            float sh[4], sc[4];
            #pragma unroll
            for (int j = 0; j < 4; j++) {
                float4 ph  = *(const float4*)red[j];
                float4 pcv = *(const float4*)red[4 + j];
                sh[j] = sqrtf(ph.x + ph.y + ph.z + ph.w);
                sc[j] = sqrtf(pcv.x + pcv.y + pcv.z + pcv.w);
            }
            softmax4(sh); softmax4(sc);
            float ha = 0.f, ca = 0.f;
            #pragma unroll
            for (int j = 0; j < 4; j++) {
                ha = fmaf(sh[j], Hr[sj[j]][u], ha);
                ca = fmaf(sc[j], Cr[sj[j]][u], ca);
            }
            float hmv = fmaxf(ha, 0.f);
            cmv = fmaxf(ca, 0.f);
            float ho = __shfl_xor(hmv, 1, 64);
            if (!(tid & 1)) {
                h2t pk; pk.x = (_Float16)hmv; pk.y = (_Float16)ho;
                hm_pk[u >> 1] = __builtin_bit_cast(unsigned int, pk);
            }
        }
        __syncthreads();                                   // (2) hm_pk ready

        // ---- C: gate GEMV, 2 cols/thread, 2-deep ping-pong pipeline ----
        {
            const uint4* p1 = (const uint4*)rkP + tid;         // stride 1024/kc
            const uint4* p2 = p1 + 512;
            float a0 = 0.f, a1 = 0.f;
            uint4 wA[8], wB[8];

            auto loadg = [&](uint4* w, int kb) {
                #pragma unroll
                for (int i = 0; i < 4; i++) {
                    w[i]     = p1[(size_t)(kb + i) * 1024];
                    w[4 + i] = p2[(size_t)(kb + i) * 1024];
                }
            };
            auto compg = [&](const uint4* w, int kb) {
                #pragma unroll
                for (int i = 0; i < 4; i++) {
                    uint4 h0 = *(const uint4*)&hm_pk[(kb + i) * 4];
                    a0 = dot8h(w[i], h0, a0);
                    a1 = dot8h(w[4 + i], h0, a1);
                }
            };
            loadg(wA, 0);
            loadg(wB, 4);   compg(wA, 0);
            loadg(wA, 8);   compg(wB, 4);
            loadg(wB, 12);  compg(wA, 8);
            loadg(wA, 16);  compg(wB, 12);
            loadg(wB, 20);  compg(wA, 16);
            loadg(wA, 24);  compg(wB, 20);
            loadg(wB, 28);  compg(wA, 24);
            compg(wB, 28);

            int q = tid >> 8;
            gtmp[q][u] = a0;
            gtmp[q + 2][u] = a1;
        }
        __syncthreads();                                   // (3) gtmp ready

        // ---- D: gate epilogue (tid < 256) ----
        if (tid < 256) {
            float g0 = gtmp[0][u] + xg0;
            float g1 = gtmp[1][u] + xg1;
            float g2 = gtmp[2][u] + xg2;
            float g3 = gtmp[3][u] + xg3;
            float gi = hsig(g0), gf = hsig(g1), gm = hsig(g2), go = hsig(g3);
            float c = gf * cmv + gi * gm;
            float h = go * ftanh(c);
            Hr[st][u] = h;
            Cr[st][u] = c;
            outs[((size_t)b * Tn + tt) * 512 + d * 256 + u] = (_Float16)h;
            float hho = __shfl_xor(h, 1, 64);
            float cco = __shfl_xor(c, 1, 64);
            if (!(tid & 1)) {
                h2t pk1; pk1.x = (_Float16)h; pk1.y = (_Float16)hho;
                h2t pk2; pk2.x = (_Float16)c; pk2.y = (_Float16)cco;
                Hpk[u >> 1] = __builtin_bit_cast(unsigned int, pk1);
                Cpk[u >> 1] = __builtin_bit_cast(unsigned int, pk2);
            }
        }
        __syncthreads();                                   // (4) Hpk/Cpk ready

        // ---- E: projection GEMVs, 2-deep ping-pong pipeline ----
        if (tid < 256) {
            const uint4* pw = (const uint4*)WhP + tid;         // stride 256/kc
            float ph = 0.f, pch = 0.f;
            uint4 wA[8], wB[8];

            auto loadg = [&](uint4* w, int kb) {
                #pragma unroll
                for (int i = 0; i < 8; i++) w[i] = pw[(size_t)(kb + i) * 256];
            };
            auto compg = [&](const uint4* w, int kb) {
                #pragma unroll
                for (int i = 0; i < 8; i++) {
                    uint4 Hv = *(const uint4*)&Hpk[(kb + i) * 4];
                    uint4 Cv = *(const uint4*)&Cpk[(kb + i) * 4];
                    ph  = dot8h(w[i], Hv, ph);
                    pch = dot8h(w[i], Cv, pch);
                }
            };
            loadg(wA, 0);
            loadg(wB, 8);   compg(wA, 0);
            loadg(wA, 16);  compg(wB, 8);
            loadg(wB, 24);  compg(wA, 16);
            compg(wB, 24);

            PHr[st][tid]  = ph;
            PChr[st][tid] = pch;
        } else {
            const int c = tid - 256;
            const uint4* pw = (const uint4*)WcP + c;
            float pcc = 0.f;
            uint4 wA[8], wB[8];

            auto loadg = [&](uint4* w, int kb) {
                #pragma unroll
                for (int i = 0; i < 8; i++) w[i] = pw[(size_t)(kb + i) * 256];
            };
            auto compg = [&](const uint4* w, int kb) {
                #pragma unroll
                for (int i = 0; i < 8; i++) {
                    uint4 Cv = *(const uint4*)&Cpk[(kb + i) * 4];
                    pcc = dot8h(w[i], Cv, pcc);
                }
            };
            loadg(wA, 0);
            loadg(wB, 8);   compg(wA, 0);
            loadg(wA, 16);  compg(wB, 8);
            loadg(wB, 24);  compg(wA, 16);
            compg(wB, 24);

            PCcr[st][c] = pcc;
        }
        __syncthreads();                                   // (5) end of step
    }
}

// ---------------------------------------------------------------------------
// Phase 3 epilogue: ha = relu(t1)@at2 ; hb = relu(t2)@at22 ;
// out = tanh(ha*outs + hb).
// ---------------------------------------------------------------------------
DEVINL void cvt8(uint4 v, float* f) {
    h2t p0 = __builtin_bit_cast(h2t, v.x), p1 = __builtin_bit_cast(h2t, v.y);
    h2t p2 = __builtin_bit_cast(h2t, v.z), p3 = __builtin_bit_cast(h2t, v.w);
    f[0] = (float)p0.x; f[1] = (float)p0.y; f[2] = (float)p1.x; f[3] = (float)p1.y;
    f[4] = (float)p2.x; f[5] = (float)p2.y; f[6] = (float)p3.x; f[7] = (float)p3.y;
}

__global__ __launch_bounds__(256)
void final2(const _Float16* __restrict__ t1, const _Float16* __restrict__ t2,
            const _Float16* __restrict__ outs16,
            const float* __restrict__ at2, const float* __restrict__ at22,
            float* __restrict__ out)
{
    __shared__ float has[8], hbs[8];
    const int tid = threadIdx.x;
    const size_t m0 = (size_t)blockIdx.x * 8;
    const int rr = tid >> 5, us = tid & 31;
    const size_t m = m0 + rr;

    uint4 v1 = *(const uint4*)(t1 + m * 256 + us * 8);
    uint4 v2 = *(const uint4*)(t2 + m * 256 + us * 8);
    float f1[8], f2[8];
    cvt8(v1, f1); cvt8(v2, f2);
    float4 wa0 = *(const float4*)(at2  + us * 8);
    float4 wa1 = *(const float4*)(at2  + us * 8 + 4);
    float4 wb0 = *(const float4*)(at22 + us * 8);
    float4 wb1 = *(const float4*)(at22 + us * 8 + 4);

    float pa = fmaxf(f1[0], 0.f) * wa0.x + fmaxf(f1[1], 0.f) * wa0.y
             + fmaxf(f1[2], 0.f) * wa0.z + fmaxf(f1[3], 0.f) * wa0.w
             + fmaxf(f1[4], 0.f) * wa1.x + fmaxf(f1[5], 0.f) * wa1.y
             + fmaxf(f1[6], 0.f) * wa1.z + fmaxf(f1[7], 0.f) * wa1.w;
    float pb = fmaxf(f2[0], 0.f) * wb0.x + fmaxf(f2[1], 0.f) * wb0.y
             + fmaxf(f2[2], 0.f) * wb0.z + fmaxf(f2[3], 0.f) * wb0.w
             + fmaxf(f2[4], 0.f) * wb1.x + fmaxf(f2[5], 0.f) * wb1.y
             + fmaxf(f2[6], 0.f) * wb1.z + fmaxf(f2[7], 0.f) * wb1.w;
    #pragma unroll
    for (int mm = 16; mm; mm >>= 1) {
        pa += __shfl_xor(pa, mm, 32);
        pb += __shfl_xor(pb, mm, 32);
    }
    if (us == 0) { has[rr] = pa; hbs[rr] = pb; }
    __syncthreads();

    for (int e = tid; e < 8 * 128; e += 256) {
        int r2 = e >> 7, k4 = (e & 127) * 4;
        size_t base = (m0 + r2) * 512 + k4;
        uint2 hv = *(const uint2*)(outs16 + base);
        h2t pA = __builtin_bit_cast(h2t, hv.x), pB = __builtin_bit_cast(h2t, hv.y);
        float hav = has[r2], hbv = hbs[r2];
        float4 o;
        o.x = ftanh(hav * (float)pA.x + hbv);
        o.y = ftanh(hav * (float)pA.y + hbv);
        o.z = ftanh(hav * (float)pB.x + hbv);
        o.w = ftanh(hav * (float)pB.y + hbv);
        *(float4*)(out + base) = o;
    }
}

// ---------------------------------------------------------------------------
extern "C" void kernel_launch(void* const* d_in, const int* in_sizes, int n_in,
                              void* d_out, int out_size, void* d_ws, size_t ws_size,
                              hipStream_t stream)
{
    (void)in_sizes; (void)n_in; (void)out_size; (void)ws_size;
    const float* x    = (const float*)d_in[0];
    const float* wk   = (const float*)d_in[1];  // kernel (F, 4U)
    const float* rk   = (const float*)d_in[2];  // recurrent_kernel (U, 4U)
    const float* ath  = (const float*)d_in[3];  // attention_h (F+U, U)
    const float* atc  = (const float*)d_in[4];  // attention_c (F+U, U)
    const float* at1  = (const float*)d_in[5];  // attention1 (2U+F, U)
    const float* at2  = (const float*)d_in[7];  // attention2 (U, 1)
    const float* at22 = (const float*)d_in[8];  // attention2_2 (U, 1)
    float* out = (float*)d_out;

    char* p = (char*)d_ws;
    auto take = [&](size_t bytes) { char* q = p; p += (bytes + 255) & ~(size_t)255; return q; };
    _Float16* xg   = (_Float16*)take((size_t)Tn * Bn * Gn * 2);   // 134 MB (t1/t2 alias after recurrence)
    _Float16* xWh  = (_Float16*)take((size_t)Tn * Bn * Un * 2);   //  33.5 MB
    _Float16* xWc  = (_Float16*)take((size_t)Tn * Bn * Un * 2);
    _Float16* A16  = (_Float16*)take((size_t)Bn * Tn * 512 * 2);  //  67 MB: outs fp16, (b,t)-major
    _Float16* xf16 = (_Float16*)take((size_t)Bn * Tn * Fn * 2);   //  67 MB
    _Float16* rkP  = (_Float16*)take((size_t)Un * Gn * 2);        // 512 KB
    _Float16* WhP  = (_Float16*)take((size_t)Un * Un * 2);
    _Float16* WcP  = (_Float16*)take((size_t)Un * Un * 2);
    _Float16* Wt1  = (_Float16*)take((size_t)Gn * Fn * 2);        //   1 MB
    _Float16* Wt2  = (_Float16*)take((size_t)Un * Fn * 2);
    _Float16* Wt3  = (_Float16*)take((size_t)Un * Fn * 2);
    _Float16* WtA  = (_Float16*)take((size_t)Un * Fn * 2);        // A11^T
    _Float16* WtB  = (_Float16*)take((size_t)Un * Fn * 2);        // A12^T
    _Float16* t1 = (_Float16*)xg;                    // alias: xg dead after recurrence
    _Float16* t2 = t1 + (size_t)Bn * Tn * Un;

    // Phase 0: packing
    pack_x<<<32768, 256, 0, stream>>>(x, xf16);
    wt_pack<<<2048, 256, 0, stream>>>(wk, Wt1, Gn);
    wt_pack<<<1024, 256, 0, stream>>>(ath + (size_t)Un * Un, Wt2, Un);
    wt_pack<<<1024, 256, 0, stream>>>(atc + (size_t)Un * Un, Wt3, Un);
    wt_pack<<<1024, 256, 0, stream>>>(at1, WtA, Un);
    wt_pack<<<1024, 256, 0, stream>>>(at1 + (size_t)512 * Un, WtB, Un);
    pack_w<<<64, 256, 0, stream>>>(rk, ath, atc, rkP, WhP, WcP);

    // Phase 1: MFMA x-projections (t-major outputs for the recurrence)
    gemm_mfma<true><<<dim3(Gn / 64, (Bn * Tn) / 64), 256, 0, stream>>>(xf16, Wt1, Gn, xg);
    gemm_mfma<true><<<dim3(Un / 64, (Bn * Tn) / 64), 256, 0, stream>>>(xf16, Wt2, Un, xWh);
    gemm_mfma<true><<<dim3(Un / 64, (Bn * Tn) / 64), 256, 0, stream>>>(xf16, Wt3, Un, xWc);

    // Phase 2: recurrence — 256 WGs (1 row each), pipelined weight streams
    recurrence<<<dim3(256), dim3(512), 0, stream>>>(xg, xWh, xWc, rkP, WhP, WcP, A16);

    // Phase 3: output attention as two MFMA GEMMs + light epilogue
    gemm_mfma<false><<<dim3(Un / 64, (Bn * Tn) / 64), 256, 0, stream>>>(A16,  WtA, Un, t1);
    gemm_mfma<false><<<dim3(Un / 64, (Bn * Tn) / 64), 256, 0, stream>>>(xf16, WtB, Un, t2);
    final2<<<(Bn * Tn) / 8, 256, 0, stream>>>(t1, t2, A16, at2, at22, out);
}

// Round 7
// 4771.152 us; speedup vs baseline: 3.4338x; 2.9062x over previous
//
#include <hip/hip_runtime.h>
#include <cstddef>
#include <cstdint>

#define DEVINL __device__ __forceinline__

constexpr int Bn = 128;   // batch
constexpr int Tn = 512;   // time
constexpr int Fn = 512;   // features
constexpr int Un = 256;   // units
constexpr int Gn = 1024;  // 4*U
constexpr int RS = 5;     // ring slots

typedef _Float16 h2t   __attribute__((ext_vector_type(2)));
typedef _Float16 half4 __attribute__((ext_vector_type(4)));
typedef _Float16 half8 __attribute__((ext_vector_type(8)));
typedef float    f32x4 __attribute__((ext_vector_type(4)));

DEVINL float ftanh(float x) { float e = __expf(2.f * x); return 1.f - 2.f / (e + 1.f); }
DEVINL float hsig(float x)  { return fminf(fmaxf(fmaf(x, 0.2f, 0.5f), 0.f), 1.f); }

DEVINL void softmax4(float* s) {
    float mx = fmaxf(fmaxf(s[0], s[1]), fmaxf(s[2], s[3]));
    float e0 = __expf(s[0] - mx), e1 = __expf(s[1] - mx);
    float e2 = __expf(s[2] - mx), e3 = __expf(s[3] - mx);
    float inv = 1.f / (e0 + e1 + e2 + e3);
    s[0] = e0 * inv; s[1] = e1 * inv; s[2] = e2 * inv; s[3] = e3 * inv;
}

// dot of 2 fp16 pairs: w (packed f16x2 as uint) . h -> acc
DEVINL float d2(unsigned int w, unsigned int h, float acc) {
#if __has_builtin(__builtin_amdgcn_fdot2)
    return __builtin_amdgcn_fdot2(__builtin_bit_cast(h2t, w), __builtin_bit_cast(h2t, h), acc, false);
#else
    h2t a = __builtin_bit_cast(h2t, w), b = __builtin_bit_cast(h2t, h);
    acc = fmaf((float)a.x, (float)b.x, acc);
    acc = fmaf((float)a.y, (float)b.y, acc);
    return acc;
#endif
}
// 8 fp16 weights (uint4) . 8 fp16 h-values (uint4) -> acc
DEVINL float dot8h(uint4 w, uint4 h, float acc) {
    acc = d2(w.x, h.x, acc);
    acc = d2(w.y, h.y, acc);
    acc = d2(w.z, h.z, acc);
    acc = d2(w.w, h.w, acc);
    return acc;
}

// ---------------------------------------------------------------------------
// pack x (fp32) -> fp16, same layout (M=B*T rows, 512 cols)
// ---------------------------------------------------------------------------
__global__ __launch_bounds__(256)
void pack_x(const float* __restrict__ x, _Float16* __restrict__ xh)
{
    size_t i = ((size_t)blockIdx.x * 256 + threadIdx.x) * 4;
    float4 v = *(const float4*)(x + i);
    half4 o;
    o.x = (_Float16)v.x; o.y = (_Float16)v.y; o.z = (_Float16)v.z; o.w = (_Float16)v.w;
    *(half4*)(xh + i) = o;
}

// ---------------------------------------------------------------------------
// pack W (K=512 rows x N cols, fp32) -> Wt (N rows x 512 cols, fp16)
// ---------------------------------------------------------------------------
__global__ __launch_bounds__(256)
void wt_pack(const float* __restrict__ W, _Float16* __restrict__ Wt, int N)
{
    int total = N * 512;
    for (int e = blockIdx.x * 256 + threadIdx.x; e < total; e += gridDim.x * 256) {
        int n = e >> 9, k = e & 511;
        Wt[e] = (_Float16)W[(size_t)k * N + n];
    }
}

// ---------------------------------------------------------------------------
// pack recurrence weights -> fp16, k-interleaved: P[(kc*N + n)*8 + i] = W[kc*8+i][n]
// ---------------------------------------------------------------------------
__global__ __launch_bounds__(256)
void pack_w(const float* __restrict__ rk, const float* __restrict__ ath,
            const float* __restrict__ atc,
            _Float16* __restrict__ rkP, _Float16* __restrict__ WhP,
            _Float16* __restrict__ WcP)
{
    int idx = blockIdx.x * 256 + threadIdx.x;
    const int stride = gridDim.x * 256;
    for (int e = idx; e < 32 * 1024 * 8; e += stride) {
        int i = e & 7, n = (e >> 3) & 1023, kc = e >> 13;
        rkP[e] = (_Float16)rk[(size_t)(kc * 8 + i) * Gn + n];
    }
    for (int e = idx; e < 32 * 256 * 8; e += stride) {
        int i = e & 7, n = (e >> 3) & 255, kc = e >> 11;
        WhP[e] = (_Float16)ath[(size_t)(kc * 8 + i) * Un + n];
        WcP[e] = (_Float16)atc[(size_t)(kc * 8 + i) * Un + n];
    }
}

// ---------------------------------------------------------------------------
// MFMA fp16 GEMM. A: (65536 x 512) fp16 row-major. Wt: (N x 512) fp16
// (pre-transposed). TMAJ: out at [(t*B+b)*N+n] (m = b*512+t); else out[m*N+n].
// ---------------------------------------------------------------------------
template<bool TMAJ>
__global__ __launch_bounds__(256)
void gemm_mfma(const _Float16* __restrict__ A, const _Float16* __restrict__ Wt,
               int N, _Float16* __restrict__ out)
{
    __shared__ __align__(16) _Float16 As[64][40];
    __shared__ __align__(16) _Float16 Bs[64][40];
    const int tid = threadIdx.x;
    const int n0 = blockIdx.x * 64, m0 = blockIdx.y * 64;
    const int w = tid >> 6, lane = tid & 63;
    const int fr = lane & 15, quad = lane >> 4;
    const int srow = tid >> 2, sk = (tid & 3) * 8;

    f32x4 acc[4];
    #pragma unroll
    for (int i = 0; i < 4; i++) acc[i] = (f32x4){0.f, 0.f, 0.f, 0.f};

    const _Float16* ap = A  + (size_t)(m0 + srow) * 512 + sk;
    const _Float16* bp = Wt + (size_t)(n0 + srow) * 512 + sk;

    for (int k0 = 0; k0 < 512; k0 += 32) {
        uint4 av = *(const uint4*)(ap + k0);
        uint4 bv = *(const uint4*)(bp + k0);
        __syncthreads();
        *(uint4*)&As[srow][sk] = av;
        *(uint4*)&Bs[srow][sk] = bv;
        __syncthreads();
        half8 a = *(const half8*)&As[w * 16 + fr][quad * 8];
        #pragma unroll
        for (int nt = 0; nt < 4; nt++) {
            half8 b = *(const half8*)&Bs[nt * 16 + fr][quad * 8];
            acc[nt] = __builtin_amdgcn_mfma_f32_16x16x32_f16(a, b, acc[nt], 0, 0, 0);
        }
    }
    #pragma unroll
    for (int nt = 0; nt < 4; nt++) {
        int n = n0 + nt * 16 + fr;
        #pragma unroll
        for (int reg = 0; reg < 4; reg++) {
            int m = m0 + w * 16 + quad * 4 + reg;
            if (TMAJ) {
                int b = m >> 9, t = m & 511;
                out[((size_t)t * Bn + b) * N + n] = (_Float16)acc[nt][reg];
            } else {
                out[(size_t)m * N + n] = (_Float16)acc[nt][reg];
            }
        }
    }
}

// ---------------------------------------------------------------------------
// Phase 2: recurrence. 256 WGs x 512 threads; WG handles ONE (dir, batch) row.
// Round-4 validated structure, ONE delta: WhP (128 KB) is loaded into dynamic
// LDS once at entry, so phase E's Wh stream comes from LDS instead of L2 —
// per-step L2 weight stream drops 768 KB -> 640 KB (the measured bound).
// ---------------------------------------------------------------------------
__global__ __launch_bounds__(512)
void recurrence(const _Float16* __restrict__ xg,
                const _Float16* __restrict__ xWh,
                const _Float16* __restrict__ xWc,
                const _Float16* __restrict__ rkP,
                const _Float16* __restrict__ WhP,
                const _Float16* __restrict__ WcP,
                _Float16* __restrict__ outs)
{
    const int tid = threadIdx.x;
    const int d = blockIdx.x >> 7;          // direction
    const int b = blockIdx.x & 127;         // batch row

    __shared__ float Hr[RS][Un], Cr[RS][Un];
    __shared__ float PHr[RS][Un], PCcr[RS][Un], PChr[RS][Un];
    __shared__ __align__(16) unsigned int hm_pk[128];  // hmix fp16x2
    __shared__ __align__(16) unsigned int Hpk[128], Cpk[128];
    __shared__ float gtmp[4][Un];
    __shared__ __align__(16) float red[8][4];

    extern __shared__ __align__(16) uint4 WhL[];   // 131072 B = WhP resident

    // one-time: WhP -> LDS (8192 uint4), plus ring zero-init
    for (int e = tid; e < 8192; e += 512) WhL[e] = ((const uint4*)WhP)[e];
    for (int e = tid; e < RS * Un; e += 512) {
        ((float*)Hr)[e] = 0.f; ((float*)Cr)[e] = 0.f;
        ((float*)PHr)[e] = 0.f; ((float*)PCcr)[e] = 0.f; ((float*)PChr)[e] = 0.f;
    }
    __syncthreads();

    const int u = tid & 255;
    const int g = tid >> 8;            // score family: 0 = h, 1 = c
    const int lane = tid & 63;
    const int gwv = (tid >> 6) & 3;    // wave index within family

    for (int t = 0; t < Tn; t++) {
        const int tt = d ? (Tn - 1 - t) : t;
        const int st = t % RS;
        int sj[4];
        #pragma unroll
        for (int j = 0; j < 4; j++) sj[j] = (t - 1 - j + 2 * RS) % RS;

        const size_t rowx = (size_t)tt * Bn + b;

        // per-thread step inputs (issued at step start; consumed late)
        float xh = (float)xWh[rowx * Un + u];
        float xc = (float)xWc[rowx * Un + u];
        float xg0 = 0.f, xg1 = 0.f, xg2 = 0.f, xg3 = 0.f;
        if (tid < 256) {
            xg0 = (float)xg[rowx * Gn + u];
            xg1 = (float)xg[rowx * Gn + Un + u];
            xg2 = (float)xg[rowx * Gn + 2 * Un + u];
            xg3 = (float)xg[rowx * Gn + 3 * Un + u];
        }

        // ---- A: scores (4 tanh per thread; family g) ----
        float vals[4];
        if (g == 0) {
            #pragma unroll
            for (int j = 0; j < 4; j++) {
                float ah = ftanh(PHr[sj[j]][u] + xh);
                vals[j] = ah * ah;
            }
        } else {
            #pragma unroll
            for (int j = 0; j < 4; j++) {
                float pc = (j < 3) ? PCcr[sj[j]][u] : PChr[sj[j]][u];
                float ac = ftanh(pc + ((j < 3) ? xc : xh));
                vals[j] = ac * ac;
            }
        }
        #pragma unroll
        for (int jj = 0; jj < 4; jj++) {
            float v = vals[jj];
            #pragma unroll
            for (int m = 32; m; m >>= 1) v += __shfl_xor(v, m, 64);
            if (lane == 0) red[g * 4 + jj][gwv] = v;
        }
        __syncthreads();                                   // (1) red ready

        // ---- B: softmax + hmix/cmix + pack (tid < 256) ----
        float cmv = 0.f;
        if (tid < 256) {
            float sh[4], sc[4];
            #pragma unroll
            for (int j = 0; j < 4; j++) {
                float4 ph  = *(const float4*)red[j];
                float4 pcv = *(const float4*)red[4 + j];
                sh[j] = sqrtf(ph.x + ph.y + ph.z + ph.w);
                sc[j] = sqrtf(pcv.x + pcv.y + pcv.z + pcv.w);
            }
            softmax4(sh); softmax4(sc);
            float ha = 0.f, ca = 0.f;
            #pragma unroll
            for (int j = 0; j < 4; j++) {
                ha = fmaf(sh[j], Hr[sj[j]][u], ha);
                ca = fmaf(sc[j], Cr[sj[j]][u], ca);
            }
            float hmv = fmaxf(ha, 0.f);
            cmv = fmaxf(ca, 0.f);
            float ho = __shfl_xor(hmv, 1, 64);
            if (!(tid & 1)) {
                h2t pk; pk.x = (_Float16)hmv; pk.y = (_Float16)ho;
                hm_pk[u >> 1] = __builtin_bit_cast(unsigned int, pk);
            }
        }
        __syncthreads();                                   // (2) hm_pk ready

        // ---- C: gate GEMV, 2 cols/thread (tid, tid+512), 1 row ----
        {
            float a0 = 0.f, a1 = 0.f;
            const _Float16* p1 = rkP + (size_t)tid * 8;
            const _Float16* p2 = rkP + (size_t)(tid + 512) * 8;
            #pragma unroll 4
            for (int kc = 0; kc < 32; kc++) {
                uint4 w1 = *(const uint4*)(p1 + (size_t)kc * 8192);
                uint4 w2 = *(const uint4*)(p2 + (size_t)kc * 8192);
                uint4 h0 = *(const uint4*)&hm_pk[kc * 4];
                a0 = dot8h(w1, h0, a0);
                a1 = dot8h(w2, h0, a1);
            }
            int q = tid >> 8;
            gtmp[q][u] = a0;
            gtmp[q + 2][u] = a1;
        }
        __syncthreads();                                   // (3) gtmp ready

        // ---- D: gate epilogue (tid < 256) ----
        if (tid < 256) {
            float g0 = gtmp[0][u] + xg0;
            float g1 = gtmp[1][u] + xg1;
            float g2 = gtmp[2][u] + xg2;
            float g3 = gtmp[3][u] + xg3;
            float gi = hsig(g0), gf = hsig(g1), gm = hsig(g2), go = hsig(g3);
            float c = gf * cmv + gi * gm;
            float h = go * ftanh(c);
            Hr[st][u] = h;
            Cr[st][u] = c;
            outs[((size_t)b * Tn + tt) * 512 + d * 256 + u] = (_Float16)h;
            float hho = __shfl_xor(h, 1, 64);
            float cco = __shfl_xor(c, 1, 64);
            if (!(tid & 1)) {
                h2t pk1; pk1.x = (_Float16)h; pk1.y = (_Float16)hho;
                h2t pk2; pk2.x = (_Float16)c; pk2.y = (_Float16)cco;
                Hpk[u >> 1] = __builtin_bit_cast(unsigned int, pk1);
                Cpk[u >> 1] = __builtin_bit_cast(unsigned int, pk2);
            }
        }
        __syncthreads();                                   // (4) Hpk/Cpk ready

        // ---- E: projection GEMVs (Wh from LDS, Wc streamed) ----
        if (tid < 256) {
            const int c = tid;
            float ph = 0.f, pch = 0.f;
            #pragma unroll 4
            for (int kc = 0; kc < 32; kc++) {
                uint4 wv4 = WhL[kc * 256 + c];
                uint4 Hv = *(const uint4*)&Hpk[kc * 4];
                uint4 Cv = *(const uint4*)&Cpk[kc * 4];
                ph  = dot8h(wv4, Hv, ph);
                pch = dot8h(wv4, Cv, pch);
            }
            PHr[st][c]  = ph;
            PChr[st][c] = pch;
        } else {
            const int c = tid - 256;
            const _Float16* pw = WcP + (size_t)c * 8;
            float pcc = 0.f;
            #pragma unroll 4
            for (int kc = 0; kc < 32; kc++) {
                uint4 wv4 = *(const uint4*)(pw + (size_t)kc * 2048);
                uint4 Cv = *(const uint4*)&Cpk[kc * 4];
                pcc = dot8h(wv4, Cv, pcc);
            }
            PCcr[st][c] = pcc;
        }
        __syncthreads();                                   // (5) end of step
    }
}

// ---------------------------------------------------------------------------
// Phase 3 epilogue: ha = relu(t1)@at2 ; hb = relu(t2)@at22 ;
// out = tanh(ha*outs + hb).
// ---------------------------------------------------------------------------
DEVINL void cvt8(uint4 v, float* f) {
    h2t p0 = __builtin_bit_cast(h2t, v.x), p1 = __builtin_bit_cast(h2t, v.y);
    h2t p2 = __builtin_bit_cast(h2t, v.z), p3 = __builtin_bit_cast(h2t, v.w);
    f[0] = (float)p0.x; f[1] = (float)p0.y; f[2] = (float)p1.x; f[3] = (float)p1.y;
    f[4] = (float)p2.x; f[5] = (float)p2.y; f[6] = (float)p3.x; f[7] = (float)p3.y;
}

__global__ __launch_bounds__(256)
void final2(const _Float16* __restrict__ t1, const _Float16* __restrict__ t2,
            const _Float16* __restrict__ outs16,
            const float* __restrict__ at2, const float* __restrict__ at22,
            float* __restrict__ out)
{
    __shared__ float has[8], hbs[8];
    const int tid = threadIdx.x;
    const size_t m0 = (size_t)blockIdx.x * 8;
    const int rr = tid >> 5, us = tid & 31;
    const size_t m = m0 + rr;

    uint4 v1 = *(const uint4*)(t1 + m * 256 + us * 8);
    uint4 v2 = *(const uint4*)(t2 + m * 256 + us * 8);
    float f1[8], f2[8];
    cvt8(v1, f1); cvt8(v2, f2);
    float4 wa0 = *(const float4*)(at2  + us * 8);
    float4 wa1 = *(const float4*)(at2  + us * 8 + 4);
    float4 wb0 = *(const float4*)(at22 + us * 8);
    float4 wb1 = *(const float4*)(at22 + us * 8 + 4);

    float pa = fmaxf(f1[0], 0.f) * wa0.x + fmaxf(f1[1], 0.f) * wa0.y
             + fmaxf(f1[2], 0.f) * wa0.z + fmaxf(f1[3], 0.f) * wa0.w
             + fmaxf(f1[4], 0.f) * wa1.x + fmaxf(f1[5], 0.f) * wa1.y
             + fmaxf(f1[6], 0.f) * wa1.z + fmaxf(f1[7], 0.f) * wa1.w;
    float pb = fmaxf(f2[0], 0.f) * wb0.x + fmaxf(f2[1], 0.f) * wb0.y
             + fmaxf(f2[2], 0.f) * wb0.z + fmaxf(f2[3], 0.f) * wb0.w
             + fmaxf(f2[4], 0.f) * wb1.x + fmaxf(f2[5], 0.f) * wb1.y
             + fmaxf(f2[6], 0.f) * wb1.z + fmaxf(f2[7], 0.f) * wb1.w;
    #pragma unroll
    for (int mm = 16; mm; mm >>= 1) {
        pa += __shfl_xor(pa, mm, 32);
        pb += __shfl_xor(pb, mm, 32);
    }
    if (us == 0) { has[rr] = pa; hbs[rr] = pb; }
    __syncthreads();

    for (int e = tid; e < 8 * 128; e += 256) {
        int r2 = e >> 7, k4 = (e & 127) * 4;
        size_t base = (m0 + r2) * 512 + k4;
        uint2 hv = *(const uint2*)(outs16 + base);
        h2t pA = __builtin_bit_cast(h2t, hv.x), pB = __builtin_bit_cast(h2t, hv.y);
        float hav = has[r2], hbv = hbs[r2];
        float4 o;
        o.x = ftanh(hav * (float)pA.x + hbv);
        o.y = ftanh(hav * (float)pA.y + hbv);
        o.z = ftanh(hav * (float)pB.x + hbv);
        o.w = ftanh(hav * (float)pB.y + hbv);
        *(float4*)(out + base) = o;
    }
}

// ---------------------------------------------------------------------------
extern "C" void kernel_launch(void* const* d_in, const int* in_sizes, int n_in,
                              void* d_out, int out_size, void* d_ws, size_t ws_size,
                              hipStream_t stream)
{
    (void)in_sizes; (void)n_in; (void)out_size; (void)ws_size;
    const float* x    = (const float*)d_in[0];
    const float* wk   = (const float*)d_in[1];  // kernel (F, 4U)
    const float* rk   = (const float*)d_in[2];  // recurrent_kernel (U, 4U)
    const float* ath  = (const float*)d_in[3];  // attention_h (F+U, U)
    const float* atc  = (const float*)d_in[4];  // attention_c (F+U, U)
    const float* at1  = (const float*)d_in[5];  // attention1 (2U+F, U)
    const float* at2  = (const float*)d_in[7];  // attention2 (U, 1)
    const float* at22 = (const float*)d_in[8];  // attention2_2 (U, 1)
    float* out = (float*)d_out;

    char* p = (char*)d_ws;
    auto take = [&](size_t bytes) { char* q = p; p += (bytes + 255) & ~(size_t)255; return q; };
    _Float16* xg   = (_Float16*)take((size_t)Tn * Bn * Gn * 2);   // 134 MB (t1/t2 alias after recurrence)
    _Float16* xWh  = (_Float16*)take((size_t)Tn * Bn * Un * 2);   //  33.5 MB
    _Float16* xWc  = (_Float16*)take((size_t)Tn * Bn * Un * 2);
    _Float16* A16  = (_Float16*)take((size_t)Bn * Tn * 512 * 2);  //  67 MB: outs fp16, (b,t)-major
    _Float16* xf16 = (_Float16*)take((size_t)Bn * Tn * Fn * 2);   //  67 MB
    _Float16* rkP  = (_Float16*)take((size_t)Un * Gn * 2);        // 512 KB
    _Float16* WhP  = (_Float16*)take((size_t)Un * Un * 2);
    _Float16* WcP  = (_Float16*)take((size_t)Un * Un * 2);
    _Float16* Wt1  = (_Float16*)take((size_t)Gn * Fn * 2);        //   1 MB
    _Float16* Wt2  = (_Float16*)take((size_t)Un * Fn * 2);
    _Float16* Wt3  = (_Float16*)take((size_t)Un * Fn * 2);
    _Float16* WtA  = (_Float16*)take((size_t)Un * Fn * 2);        // A11^T
    _Float16* WtB  = (_Float16*)take((size_t)Un * Fn * 2);        // A12^T
    _Float16* t1 = (_Float16*)xg;                    // alias: xg dead after recurrence
    _Float16* t2 = t1 + (size_t)Bn * Tn * Un;

    // Phase 0: packing
    pack_x<<<32768, 256, 0, stream>>>(x, xf16);
    wt_pack<<<2048, 256, 0, stream>>>(wk, Wt1, Gn);
    wt_pack<<<1024, 256, 0, stream>>>(ath + (size_t)Un * Un, Wt2, Un);
    wt_pack<<<1024, 256, 0, stream>>>(atc + (size_t)Un * Un, Wt3, Un);
    wt_pack<<<1024, 256, 0, stream>>>(at1, WtA, Un);
    wt_pack<<<1024, 256, 0, stream>>>(at1 + (size_t)512 * Un, WtB, Un);
    pack_w<<<64, 256, 0, stream>>>(rk, ath, atc, rkP, WhP, WcP);

    // Phase 1: MFMA x-projections (t-major outputs for the recurrence)
    gemm_mfma<true><<<dim3(Gn / 64, (Bn * Tn) / 64), 256, 0, stream>>>(xf16, Wt1, Gn, xg);
    gemm_mfma<true><<<dim3(Un / 64, (Bn * Tn) / 64), 256, 0, stream>>>(xf16, Wt2, Un, xWh);
    gemm_mfma<true><<<dim3(Un / 64, (Bn * Tn) / 64), 256, 0, stream>>>(xf16, Wt3, Un, xWc);

    // Phase 2: recurrence — round-4 structure + WhP resident in 128 KB dyn LDS
    hipFuncSetAttribute(reinterpret_cast<const void*>(recurrence),
                        hipFuncAttributeMaxDynamicSharedMemorySize, 131072);
    recurrence<<<dim3(256), dim3(512), 131072, stream>>>(xg, xWh, xWc, rkP, WhP, WcP, A16);

    // Phase 3: output attention as two MFMA GEMMs + light epilogue
    gemm_mfma<false><<<dim3(Un / 64, (Bn * Tn) / 64), 256, 0, stream>>>(A16,  WtA, Un, t1);
    gemm_mfma<false><<<dim3(Un / 64, (Bn * Tn) / 64), 256, 0, stream>>>(xf16, WtB, Un, t2);
    final2<<<(Bn * Tn) / 8, 256, 0, stream>>>(t1, t2, A16, at2, at22, out);
}

// Round 8
// 4650.614 us; speedup vs baseline: 3.5228x; 1.0259x over previous
//
#include <hip/hip_runtime.h>
#include <cstddef>
#include <cstdint>

#define DEVINL __device__ __forceinline__

constexpr int Bn = 128;   // batch
constexpr int Tn = 512;   // time
constexpr int Fn = 512;   // features
constexpr int Un = 256;   // units
constexpr int Gn = 1024;  // 4*U
constexpr int RS = 5;     // ring slots

typedef _Float16 h2t   __attribute__((ext_vector_type(2)));
typedef _Float16 half4 __attribute__((ext_vector_type(4)));
typedef _Float16 half8 __attribute__((ext_vector_type(8)));
typedef float    f32x4 __attribute__((ext_vector_type(4)));

DEVINL float ftanh(float x) { float e = __expf(2.f * x); return 1.f - 2.f / (e + 1.f); }
DEVINL float hsig(float x)  { return fminf(fmaxf(fmaf(x, 0.2f, 0.5f), 0.f), 1.f); }

DEVINL void softmax4(float* s) {
    float mx = fmaxf(fmaxf(s[0], s[1]), fmaxf(s[2], s[3]));
    float e0 = __expf(s[0] - mx), e1 = __expf(s[1] - mx);
    float e2 = __expf(s[2] - mx), e3 = __expf(s[3] - mx);
    float inv = 1.f / (e0 + e1 + e2 + e3);
    s[0] = e0 * inv; s[1] = e1 * inv; s[2] = e2 * inv; s[3] = e3 * inv;
}

// dot of 2 fp16 pairs: w (packed f16x2 as uint) . h -> acc
DEVINL float d2(unsigned int w, unsigned int h, float acc) {
#if __has_builtin(__builtin_amdgcn_fdot2)
    return __builtin_amdgcn_fdot2(__builtin_bit_cast(h2t, w), __builtin_bit_cast(h2t, h), acc, false);
#else
    h2t a = __builtin_bit_cast(h2t, w), b = __builtin_bit_cast(h2t, h);
    acc = fmaf((float)a.x, (float)b.x, acc);
    acc = fmaf((float)a.y, (float)b.y, acc);
    return acc;
#endif
}
// 8 fp16 weights (uint4) . 8 fp16 h-values (uint4) -> acc
DEVINL float dot8h(uint4 w, uint4 h, float acc) {
    acc = d2(w.x, h.x, acc);
    acc = d2(w.y, h.y, acc);
    acc = d2(w.z, h.z, acc);
    acc = d2(w.w, h.w, acc);
    return acc;
}

// ---------------------------------------------------------------------------
// pack x (fp32) -> fp16, same layout (M=B*T rows, 512 cols)
// ---------------------------------------------------------------------------
__global__ __launch_bounds__(256)
void pack_x(const float* __restrict__ x, _Float16* __restrict__ xh)
{
    size_t i = ((size_t)blockIdx.x * 256 + threadIdx.x) * 4;
    float4 v = *(const float4*)(x + i);
    half4 o;
    o.x = (_Float16)v.x; o.y = (_Float16)v.y; o.z = (_Float16)v.z; o.w = (_Float16)v.w;
    *(half4*)(xh + i) = o;
}

// ---------------------------------------------------------------------------
// pack W (K=512 rows x N cols, fp32) -> Wt (N rows x 512 cols, fp16)
// ---------------------------------------------------------------------------
__global__ __launch_bounds__(256)
void wt_pack(const float* __restrict__ W, _Float16* __restrict__ Wt, int N)
{
    int total = N * 512;
    for (int e = blockIdx.x * 256 + threadIdx.x; e < total; e += gridDim.x * 256) {
        int n = e >> 9, k = e & 511;
        Wt[e] = (_Float16)W[(size_t)k * N + n];
    }
}

// ---------------------------------------------------------------------------
// pack recurrence weights -> fp16, k-interleaved: P[(kc*N + n)*8 + i] = W[kc*8+i][n]
// ---------------------------------------------------------------------------
__global__ __launch_bounds__(256)
void pack_w(const float* __restrict__ rk, const float* __restrict__ ath,
            const float* __restrict__ atc,
            _Float16* __restrict__ rkP, _Float16* __restrict__ WhP,
            _Float16* __restrict__ WcP)
{
    int idx = blockIdx.x * 256 + threadIdx.x;
    const int stride = gridDim.x * 256;
    for (int e = idx; e < 32 * 1024 * 8; e += stride) {
        int i = e & 7, n = (e >> 3) & 1023, kc = e >> 13;
        rkP[e] = (_Float16)rk[(size_t)(kc * 8 + i) * Gn + n];
    }
    for (int e = idx; e < 32 * 256 * 8; e += stride) {
        int i = e & 7, n = (e >> 3) & 255, kc = e >> 11;
        WhP[e] = (_Float16)ath[(size_t)(kc * 8 + i) * Un + n];
        WcP[e] = (_Float16)atc[(size_t)(kc * 8 + i) * Un + n];
    }
}

// ---------------------------------------------------------------------------
// MFMA fp16 GEMM. A: (65536 x 512) fp16 row-major. Wt: (N x 512) fp16
// (pre-transposed). TMAJ: out at [(t*B+b)*N+n] (m = b*512+t); else out[m*N+n].
// ---------------------------------------------------------------------------
template<bool TMAJ>
__global__ __launch_bounds__(256)
void gemm_mfma(const _Float16* __restrict__ A, const _Float16* __restrict__ Wt,
               int N, _Float16* __restrict__ out)
{
    __shared__ __align__(16) _Float16 As[64][40];
    __shared__ __align__(16) _Float16 Bs[64][40];
    const int tid = threadIdx.x;
    const int n0 = blockIdx.x * 64, m0 = blockIdx.y * 64;
    const int w = tid >> 6, lane = tid & 63;
    const int fr = lane & 15, quad = lane >> 4;
    const int srow = tid >> 2, sk = (tid & 3) * 8;

    f32x4 acc[4];
    #pragma unroll
    for (int i = 0; i < 4; i++) acc[i] = (f32x4){0.f, 0.f, 0.f, 0.f};

    const _Float16* ap = A  + (size_t)(m0 + srow) * 512 + sk;
    const _Float16* bp = Wt + (size_t)(n0 + srow) * 512 + sk;

    for (int k0 = 0; k0 < 512; k0 += 32) {
        uint4 av = *(const uint4*)(ap + k0);
        uint4 bv = *(const uint4*)(bp + k0);
        __syncthreads();
        *(uint4*)&As[srow][sk] = av;
        *(uint4*)&Bs[srow][sk] = bv;
        __syncthreads();
        half8 a = *(const half8*)&As[w * 16 + fr][quad * 8];
        #pragma unroll
        for (int nt = 0; nt < 4; nt++) {
            half8 b = *(const half8*)&Bs[nt * 16 + fr][quad * 8];
            acc[nt] = __builtin_amdgcn_mfma_f32_16x16x32_f16(a, b, acc[nt], 0, 0, 0);
        }
    }
    #pragma unroll
    for (int nt = 0; nt < 4; nt++) {
        int n = n0 + nt * 16 + fr;
        #pragma unroll
        for (int reg = 0; reg < 4; reg++) {
            int m = m0 + w * 16 + quad * 4 + reg;
            if (TMAJ) {
                int b = m >> 9, t = m & 511;
                out[((size_t)t * Bn + b) * N + n] = (_Float16)acc[nt][reg];
            } else {
                out[(size_t)m * N + n] = (_Float16)acc[nt][reg];
            }
        }
    }
}

// ---------------------------------------------------------------------------
// Phase 2: recurrence. 256 WGs x 1024 threads (16 waves, 4/SIMD); WG handles
// ONE (dir,batch) row. Round-7 phase skeleton + Wh LDS residency unchanged;
// only work-assignment widened:
//   A: 4-way split (family x j-pair) -> 2 tanh/thread
//   C: gate GEMV 1 col/thread (1024 cols) -> 4 streaming waves/SIMD
//   B/D/E: identical to round 7 (tid<256 / tid in [256,512))
// ---------------------------------------------------------------------------
__global__ __launch_bounds__(1024)
void recurrence(const _Float16* __restrict__ xg,
                const _Float16* __restrict__ xWh,
                const _Float16* __restrict__ xWc,
                const _Float16* __restrict__ rkP,
                const _Float16* __restrict__ WhP,
                const _Float16* __restrict__ WcP,
                _Float16* __restrict__ outs)
{
    const int tid = threadIdx.x;
    const int d = blockIdx.x >> 7;          // direction
    const int b = blockIdx.x & 127;         // batch row

    __shared__ float Hr[RS][Un], Cr[RS][Un];
    __shared__ float PHr[RS][Un], PCcr[RS][Un], PChr[RS][Un];
    __shared__ __align__(16) unsigned int hm_pk[128];  // hmix fp16x2
    __shared__ __align__(16) unsigned int Hpk[128], Cpk[128];
    __shared__ float gtmp[4][Un];
    __shared__ __align__(16) float red[8][4];

    extern __shared__ __align__(16) uint4 WhL[];   // 131072 B = WhP resident

    // one-time: WhP -> LDS (8192 uint4), plus ring zero-init
    for (int e = tid; e < 8192; e += 1024) WhL[e] = ((const uint4*)WhP)[e];
    for (int e = tid; e < RS * Un; e += 1024) {
        ((float*)Hr)[e] = 0.f; ((float*)Cr)[e] = 0.f;
        ((float*)PHr)[e] = 0.f; ((float*)PCcr)[e] = 0.f; ((float*)PChr)[e] = 0.f;
    }
    __syncthreads();

    const int u    = tid & 255;
    const int fam  = tid >> 9;         // 0 = h-scores, 1 = c-scores
    const int jj2  = (tid >> 8) & 1;   // j-pair within family
    const int lane = tid & 63;
    const int gwv  = (tid >> 6) & 3;   // wave index within (fam,jj2) group

    for (int t = 0; t < Tn; t++) {
        const int tt = d ? (Tn - 1 - t) : t;
        const int st = t % RS;
        int sj[4];
        #pragma unroll
        for (int j = 0; j < 4; j++) sj[j] = (t - 1 - j + 2 * RS) % RS;

        const size_t rowx = (size_t)tt * Bn + b;

        // per-thread step inputs (issued at step start; consumed late)
        float xh = (float)xWh[rowx * Un + u];
        float xc = (fam == 1) ? (float)xWc[rowx * Un + u] : 0.f;
        float xg0 = 0.f, xg1 = 0.f, xg2 = 0.f, xg3 = 0.f;
        if (tid < 256) {
            xc  = (float)xWc[rowx * Un + u];   // needed in phase B softmax path
            xg0 = (float)xg[rowx * Gn + u];
            xg1 = (float)xg[rowx * Gn + Un + u];
            xg2 = (float)xg[rowx * Gn + 2 * Un + u];
            xg3 = (float)xg[rowx * Gn + 3 * Un + u];
        }

        // ---- A: scores (2 tanh per thread; (fam, j-pair) split) ----
        float vals[2];
        #pragma unroll
        for (int jj = 0; jj < 2; jj++) {
            int j = jj2 * 2 + jj;
            float a;
            if (fam == 0) {
                a = ftanh(PHr[sj[j]][u] + xh);
            } else {
                float pc = (j < 3) ? PCcr[sj[j]][u] : PChr[sj[j]][u];
                a = ftanh(pc + ((j < 3) ? xc : xh));
            }
            vals[jj] = a * a;
        }
        #pragma unroll
        for (int jj = 0; jj < 2; jj++) {
            float v = vals[jj];
            #pragma unroll
            for (int m = 32; m; m >>= 1) v += __shfl_xor(v, m, 64);
            if (lane == 0) red[fam * 4 + jj2 * 2 + jj][gwv] = v;
        }
        __syncthreads();                                   // (1) red ready

        // ---- B: softmax + hmix/cmix + pack (tid < 256) ----
        float cmv = 0.f;
        if (tid < 256) {
            float sh[4], sc[4];
            #pragma unroll
            for (int j = 0; j < 4; j++) {
                float4 ph  = *(const float4*)red[j];
                float4 pcv = *(const float4*)red[4 + j];
                sh[j] = sqrtf(ph.x + ph.y + ph.z + ph.w);
                sc[j] = sqrtf(pcv.x + pcv.y + pcv.z + pcv.w);
            }
            softmax4(sh); softmax4(sc);
            float ha = 0.f, ca = 0.f;
            #pragma unroll
            for (int j = 0; j < 4; j++) {
                ha = fmaf(sh[j], Hr[sj[j]][u], ha);
                ca = fmaf(sc[j], Cr[sj[j]][u], ca);
            }
            float hmv = fmaxf(ha, 0.f);
            cmv = fmaxf(ca, 0.f);
            float ho = __shfl_xor(hmv, 1, 64);
            if (!(tid & 1)) {
                h2t pk; pk.x = (_Float16)hmv; pk.y = (_Float16)ho;
                hm_pk[u >> 1] = __builtin_bit_cast(unsigned int, pk);
            }
        }
        __syncthreads();                                   // (2) hm_pk ready

        // ---- C: gate GEMV, 1 col per thread (col = tid) ----
        {
            float a0 = 0.f;
            const _Float16* p1 = rkP + (size_t)tid * 8;
            #pragma unroll 4
            for (int kc = 0; kc < 32; kc++) {
                uint4 w1 = *(const uint4*)(p1 + (size_t)kc * 8192);
                uint4 h0 = *(const uint4*)&hm_pk[kc * 4];
                a0 = dot8h(w1, h0, a0);
            }
            gtmp[tid >> 8][u] = a0;
        }
        __syncthreads();                                   // (3) gtmp ready

        // ---- D: gate epilogue (tid < 256) ----
        if (tid < 256) {
            float g0 = gtmp[0][u] + xg0;
            float g1 = gtmp[1][u] + xg1;
            float g2 = gtmp[2][u] + xg2;
            float g3 = gtmp[3][u] + xg3;
            float gi = hsig(g0), gf = hsig(g1), gm = hsig(g2), go = hsig(g3);
            float c = gf * cmv + gi * gm;
            float h = go * ftanh(c);
            Hr[st][u] = h;
            Cr[st][u] = c;
            outs[((size_t)b * Tn + tt) * 512 + d * 256 + u] = (_Float16)h;
            float hho = __shfl_xor(h, 1, 64);
            float cco = __shfl_xor(c, 1, 64);
            if (!(tid & 1)) {
                h2t pk1; pk1.x = (_Float16)h; pk1.y = (_Float16)hho;
                h2t pk2; pk2.x = (_Float16)c; pk2.y = (_Float16)cco;
                Hpk[u >> 1] = __builtin_bit_cast(unsigned int, pk1);
                Cpk[u >> 1] = __builtin_bit_cast(unsigned int, pk2);
            }
        }
        __syncthreads();                                   // (4) Hpk/Cpk ready

        // ---- E: projection GEMVs (Wh from LDS, Wc streamed) ----
        if (tid < 256) {
            const int c = tid;
            float ph = 0.f, pch = 0.f;
            #pragma unroll 4
            for (int kc = 0; kc < 32; kc++) {
                uint4 wv4 = WhL[kc * 256 + c];
                uint4 Hv = *(const uint4*)&Hpk[kc * 4];
                uint4 Cv = *(const uint4*)&Cpk[kc * 4];
                ph  = dot8h(wv4, Hv, ph);
                pch = dot8h(wv4, Cv, pch);
            }
            PHr[st][c]  = ph;
            PChr[st][c] = pch;
        } else if (tid < 512) {
            const int c = tid - 256;
            const _Float16* pw = WcP + (size_t)c * 8;
            float pcc = 0.f;
            #pragma unroll 4
            for (int kc = 0; kc < 32; kc++) {
                uint4 wv4 = *(const uint4*)(pw + (size_t)kc * 2048);
                uint4 Cv = *(const uint4*)&Cpk[kc * 4];
                pcc = dot8h(wv4, Cv, pcc);
            }
            PCcr[st][c] = pcc;
        }
        __syncthreads();                                   // (5) end of step
    }
}

// ---------------------------------------------------------------------------
// Phase 3 epilogue: ha = relu(t1)@at2 ; hb = relu(t2)@at22 ;
// out = tanh(ha*outs + hb).
// ---------------------------------------------------------------------------
DEVINL void cvt8(uint4 v, float* f) {
    h2t p0 = __builtin_bit_cast(h2t, v.x), p1 = __builtin_bit_cast(h2t, v.y);
    h2t p2 = __builtin_bit_cast(h2t, v.z), p3 = __builtin_bit_cast(h2t, v.w);
    f[0] = (float)p0.x; f[1] = (float)p0.y; f[2] = (float)p1.x; f[3] = (float)p1.y;
    f[4] = (float)p2.x; f[5] = (float)p2.y; f[6] = (float)p3.x; f[7] = (float)p3.y;
}

__global__ __launch_bounds__(256)
void final2(const _Float16* __restrict__ t1, const _Float16* __restrict__ t2,
            const _Float16* __restrict__ outs16,
            const float* __restrict__ at2, const float* __restrict__ at22,
            float* __restrict__ out)
{
    __shared__ float has[8], hbs[8];
    const int tid = threadIdx.x;
    const size_t m0 = (size_t)blockIdx.x * 8;
    const int rr = tid >> 5, us = tid & 31;
    const size_t m = m0 + rr;

    uint4 v1 = *(const uint4*)(t1 + m * 256 + us * 8);
    uint4 v2 = *(const uint4*)(t2 + m * 256 + us * 8);
    float f1[8], f2[8];
    cvt8(v1, f1); cvt8(v2, f2);
    float4 wa0 = *(const float4*)(at2  + us * 8);
    float4 wa1 = *(const float4*)(at2  + us * 8 + 4);
    float4 wb0 = *(const float4*)(at22 + us * 8);
    float4 wb1 = *(const float4*)(at22 + us * 8 + 4);

    float pa = fmaxf(f1[0], 0.f) * wa0.x + fmaxf(f1[1], 0.f) * wa0.y
             + fmaxf(f1[2], 0.f) * wa0.z + fmaxf(f1[3], 0.f) * wa0.w
             + fmaxf(f1[4], 0.f) * wa1.x + fmaxf(f1[5], 0.f) * wa1.y
             + fmaxf(f1[6], 0.f) * wa1.z + fmaxf(f1[7], 0.f) * wa1.w;
    float pb = fmaxf(f2[0], 0.f) * wb0.x + fmaxf(f2[1], 0.f) * wb0.y
             + fmaxf(f2[2], 0.f) * wb0.z + fmaxf(f2[3], 0.f) * wb0.w
             + fmaxf(f2[4], 0.f) * wb1.x + fmaxf(f2[5], 0.f) * wb1.y
             + fmaxf(f2[6], 0.f) * wb1.z + fmaxf(f2[7], 0.f) * wb1.w;
    #pragma unroll
    for (int mm = 16; mm; mm >>= 1) {
        pa += __shfl_xor(pa, mm, 32);
        pb += __shfl_xor(pb, mm, 32);
    }
    if (us == 0) { has[rr] = pa; hbs[rr] = pb; }
    __syncthreads();

    for (int e = tid; e < 8 * 128; e += 256) {
        int r2 = e >> 7, k4 = (e & 127) * 4;
        size_t base = (m0 + r2) * 512 + k4;
        uint2 hv = *(const uint2*)(outs16 + base);
        h2t pA = __builtin_bit_cast(h2t, hv.x), pB = __builtin_bit_cast(h2t, hv.y);
        float hav = has[r2], hbv = hbs[r2];
        float4 o;
        o.x = ftanh(hav * (float)pA.x + hbv);
        o.y = ftanh(hav * (float)pA.y + hbv);
        o.z = ftanh(hav * (float)pB.x + hbv);
        o.w = ftanh(hav * (float)pB.y + hbv);
        *(float4*)(out + base) = o;
    }
}

// ---------------------------------------------------------------------------
extern "C" void kernel_launch(void* const* d_in, const int* in_sizes, int n_in,
                              void* d_out, int out_size, void* d_ws, size_t ws_size,
                              hipStream_t stream)
{
    (void)in_sizes; (void)n_in; (void)out_size; (void)ws_size;
    const float* x    = (const float*)d_in[0];
    const float* wk   = (const float*)d_in[1];  // kernel (F, 4U)
    const float* rk   = (const float*)d_in[2];  // recurrent_kernel (U, 4U)
    const float* ath  = (const float*)d_in[3];  // attention_h (F+U, U)
    const float* atc  = (const float*)d_in[4];  // attention_c (F+U, U)
    const float* at1  = (const float*)d_in[5];  // attention1 (2U+F, U)
    const float* at2  = (const float*)d_in[7];  // attention2 (U, 1)
    const float* at22 = (const float*)d_in[8];  // attention2_2 (U, 1)
    float* out = (float*)d_out;

    char* p = (char*)d_ws;
    auto take = [&](size_t bytes) { char* q = p; p += (bytes + 255) & ~(size_t)255; return q; };
    _Float16* xg   = (_Float16*)take((size_t)Tn * Bn * Gn * 2);   // 134 MB (t1/t2 alias after recurrence)
    _Float16* xWh  = (_Float16*)take((size_t)Tn * Bn * Un * 2);   //  33.5 MB
    _Float16* xWc  = (_Float16*)take((size_t)Tn * Bn * Un * 2);
    _Float16* A16  = (_Float16*)take((size_t)Bn * Tn * 512 * 2);  //  67 MB: outs fp16, (b,t)-major
    _Float16* xf16 = (_Float16*)take((size_t)Bn * Tn * Fn * 2);   //  67 MB
    _Float16* rkP  = (_Float16*)take((size_t)Un * Gn * 2);        // 512 KB
    _Float16* WhP  = (_Float16*)take((size_t)Un * Un * 2);
    _Float16* WcP  = (_Float16*)take((size_t)Un * Un * 2);
    _Float16* Wt1  = (_Float16*)take((size_t)Gn * Fn * 2);        //   1 MB
    _Float16* Wt2  = (_Float16*)take((size_t)Un * Fn * 2);
    _Float16* Wt3  = (_Float16*)take((size_t)Un * Fn * 2);
    _Float16* WtA  = (_Float16*)take((size_t)Un * Fn * 2);        // A11^T
    _Float16* WtB  = (_Float16*)take((size_t)Un * Fn * 2);        // A12^T
    _Float16* t1 = (_Float16*)xg;                    // alias: xg dead after recurrence
    _Float16* t2 = t1 + (size_t)Bn * Tn * Un;

    // Phase 0: packing
    pack_x<<<32768, 256, 0, stream>>>(x, xf16);
    wt_pack<<<2048, 256, 0, stream>>>(wk, Wt1, Gn);
    wt_pack<<<1024, 256, 0, stream>>>(ath + (size_t)Un * Un, Wt2, Un);
    wt_pack<<<1024, 256, 0, stream>>>(atc + (size_t)Un * Un, Wt3, Un);
    wt_pack<<<1024, 256, 0, stream>>>(at1, WtA, Un);
    wt_pack<<<1024, 256, 0, stream>>>(at1 + (size_t)512 * Un, WtB, Un);
    pack_w<<<64, 256, 0, stream>>>(rk, ath, atc, rkP, WhP, WcP);

    // Phase 1: MFMA x-projections (t-major outputs for the recurrence)
    gemm_mfma<true><<<dim3(Gn / 64, (Bn * Tn) / 64), 256, 0, stream>>>(xf16, Wt1, Gn, xg);
    gemm_mfma<true><<<dim3(Un / 64, (Bn * Tn) / 64), 256, 0, stream>>>(xf16, Wt2, Un, xWh);
    gemm_mfma<true><<<dim3(Un / 64, (Bn * Tn) / 64), 256, 0, stream>>>(xf16, Wt3, Un, xWc);

    // Phase 2: recurrence — 256 WGs x 1024 threads, Wh resident in dyn LDS
    hipFuncSetAttribute(reinterpret_cast<const void*>(recurrence),
                        hipFuncAttributeMaxDynamicSharedMemorySize, 131072);
    recurrence<<<dim3(256), dim3(1024), 131072, stream>>>(xg, xWh, xWc, rkP, WhP, WcP, A16);

    // Phase 3: output attention as two MFMA GEMMs + light epilogue
    gemm_mfma<false><<<dim3(Un / 64, (Bn * Tn) / 64), 256, 0, stream>>>(A16,  WtA, Un, t1);
    gemm_mfma<false><<<dim3(Un / 64, (Bn * Tn) / 64), 256, 0, stream>>>(xf16, WtB, Un, t2);
    final2<<<(Bn * Tn) / 8, 256, 0, stream>>>(t1, t2, A16, at2, at22, out);
}